// Round 1
// baseline (841.567 us; speedup 1.0000x reference)
//
#include <hip/hip_runtime.h>

typedef unsigned short ushort_t;
typedef unsigned int uint_t;

#define T_TOK 8192
#define HDIM 1024
#define IDIM 2048
#define NEXP 8
#define BM 128
#define BN 128
#define BK 32
#define RPAD (T_TOK + NEXP * BM)   // 9216 worst-case padded routed rows

using f32x4 = __attribute__((ext_vector_type(4))) float;
using s16x8 = __attribute__((ext_vector_type(8))) short;

__device__ __forceinline__ float b2f(ushort_t h) {
    return __uint_as_float(((uint_t)h) << 16);
}
__device__ __forceinline__ ushort_t f2bf(float f) {
    uint_t u = __float_as_uint(f);
    uint_t r = (u + 0x7FFFu + ((u >> 16) & 1u)) >> 16;
    return (ushort_t)r;
}

__device__ __forceinline__ void gload16(const void* g, void* l) {
    __builtin_amdgcn_global_load_lds(
        (const __attribute__((address_space(1))) void*)g,
        (__attribute__((address_space(3))) void*)l, 16, 0, 0);
}

// ---------------- transpose + fp32->bf16 convert: src[b][R][C] f32 -> dst[b][C][R] bf16
__global__ void tcvt(const float* __restrict__ src, ushort_t* __restrict__ dst, int R, int C) {
    __shared__ float tile[32][33];
    size_t bo = (size_t)blockIdx.z * R * C;
    int c0 = blockIdx.x * 32, r0 = blockIdx.y * 32;
    int tx = threadIdx.x, ty = threadIdx.y;
#pragma unroll
    for (int i = 0; i < 32; i += 8)
        tile[ty + i][tx] = src[bo + (size_t)(r0 + ty + i) * C + c0 + tx];
    __syncthreads();
#pragma unroll
    for (int i = 0; i < 32; i += 8)
        dst[bo + (size_t)(c0 + ty + i) * R + r0 + tx] = f2bf(tile[tx][ty + i]);
}

// ---------------- layernorm + router (block per token)
__global__ void ln_router(const float* __restrict__ x, const float* __restrict__ lnw,
                          const float* __restrict__ lnb, const float* __restrict__ rw,
                          ushort_t* __restrict__ normed, int* __restrict__ top_idx,
                          float* __restrict__ top_score, int* __restrict__ cnt) {
    int t = blockIdx.x, tid = threadIdx.x;
    const float* xr = x + (size_t)t * HDIM;
    float v[4];
    float s = 0.f, ss = 0.f;
#pragma unroll
    for (int i = 0; i < 4; i++) {
        v[i] = xr[tid + i * 256];
        s += v[i];
        ss += v[i] * v[i];
    }
#pragma unroll
    for (int o = 32; o; o >>= 1) {
        s += __shfl_down(s, o);
        ss += __shfl_down(ss, o);
    }
    __shared__ float rs_[4], rss_[4], stats[2];
    int wid = tid >> 6, lane = tid & 63;
    if (!lane) { rs_[wid] = s; rss_[wid] = ss; }
    __syncthreads();
    if (!tid) {
        float S = rs_[0] + rs_[1] + rs_[2] + rs_[3];
        float SS = rss_[0] + rss_[1] + rss_[2] + rss_[3];
        float mu = S * (1.f / HDIM);
        float var = SS * (1.f / HDIM) - mu * mu;
        stats[0] = mu;
        stats[1] = rsqrtf(var + 1e-5f);
    }
    __syncthreads();
    float mu = stats[0], rsg = stats[1];
    float lg[8] = {0, 0, 0, 0, 0, 0, 0, 0};
#pragma unroll
    for (int i = 0; i < 4; i++) {
        int h = tid + i * 256;
        float xn = (v[i] - mu) * rsg * lnw[h] + lnb[h];
        normed[(size_t)t * HDIM + h] = f2bf(xn);
        const float* rwh = rw + (size_t)h * NEXP;
#pragma unroll
        for (int e = 0; e < 8; e++) lg[e] += xn * rwh[e];
    }
#pragma unroll
    for (int o = 32; o; o >>= 1)
#pragma unroll
        for (int e = 0; e < 8; e++) lg[e] += __shfl_down(lg[e], o);
    __shared__ float lred[4][8];
    if (!lane)
#pragma unroll
        for (int e = 0; e < 8; e++) lred[wid][e] = lg[e];
    __syncthreads();
    if (!tid) {
        float best = -1e30f;
        int bi = 0;
#pragma unroll
        for (int e = 0; e < 8; e++) {
            float L = lred[0][e] + lred[1][e] + lred[2][e] + lred[3][e];
            if (L > best) { best = L; bi = e; }
        }
        top_idx[t] = bi;
        top_score[t] = 1.f / (1.f + __expf(-best));
        atomicAdd(&cnt[bi], 1);
    }
}

// ---------------- exclusive scan of padded segment offsets
__global__ void scan_k(const int* __restrict__ cnt, int* __restrict__ pad_off,
                       int* __restrict__ fill) {
    if (threadIdx.x == 0) {
        int o = 0;
        for (int e = 0; e < NEXP; e++) {
            pad_off[e] = o;
            o += (cnt[e] + BM - 1) & ~(BM - 1);
        }
        pad_off[NEXP] = o;
    }
    if (threadIdx.x < NEXP) fill[threadIdx.x] = 0;
}

// ---------------- gather tokens into sorted, score-scaled rows
__global__ void scatter_k(const ushort_t* __restrict__ normed, const int* __restrict__ top_idx,
                          const float* __restrict__ top_score, const int* __restrict__ pad_off,
                          int* __restrict__ fill, int* __restrict__ order,
                          ushort_t* __restrict__ xs) {
    int t = blockIdx.x, tid = threadIdx.x;
    __shared__ int spos;
    if (!tid) {
        int e = top_idx[t];
        int p = pad_off[e] + atomicAdd(&fill[e], 1);
        order[p] = t;
        spos = p;
    }
    __syncthreads();
    int pos = spos;
    float sc = top_score[t];
    const ushort4* src = (const ushort4*)(normed + (size_t)t * HDIM);
    ushort4* dst = (ushort4*)(xs + (size_t)pos * HDIM);
    ushort4 a = src[tid];
    a.x = f2bf(b2f(a.x) * sc);
    a.y = f2bf(b2f(a.y) * sc);
    a.z = f2bf(b2f(a.z) * sc);
    a.w = f2bf(b2f(a.w) * sc);
    dst[tid] = a;
}

// ---------------- GEMM1: hmid = silu(A@Wg) * (A@Wu), A[M][1024] bf16, W* transposed [2048][1024] bf16
__global__ __launch_bounds__(256) void gemm1_k(const ushort_t* __restrict__ A,
                                               const ushort_t* __restrict__ Wg,
                                               const ushort_t* __restrict__ Wu,
                                               const int* __restrict__ pad_off,
                                               ushort_t* __restrict__ hmid) {
    __shared__ ushort_t As[BM * BK], Bg[BN * BK], Bu[BN * BK];
    int rt = blockIdx.x, ct = blockIdx.y;
    int row0 = rt * BM;
    const ushort_t* wg = Wg;
    const ushort_t* wu = Wu;
    if (pad_off) {
        if (row0 >= pad_off[NEXP]) return;
        int e = 0;
        while (row0 >= pad_off[e + 1]) ++e;
        size_t wo = (size_t)e * IDIM * HDIM;
        wg += wo;
        wu += wo;
    }
    const int tid = threadIdx.x, l = tid & 63, wid = tid >> 6;
    const int wm = wid >> 1, wn = wid & 1, lr = l & 15, lk = l >> 4;
    f32x4 accg[4][4] = {};
    f32x4 accu[4][4] = {};
    const int c0 = tid, c1 = tid + 256;
    const int r0c = c0 >> 2, o0 = (c0 & 3) * 8, r1c = c1 >> 2, o1 = (c1 & 3) * 8;
    const int K = HDIM;
    for (int kt = 0; kt < K; kt += BK) {
        __syncthreads();
        gload16(A + (size_t)(row0 + r0c) * K + kt + o0, &As[c0 * 8]);
        gload16(A + (size_t)(row0 + r1c) * K + kt + o1, &As[c1 * 8]);
        gload16(wg + (size_t)(ct * BN + r0c) * K + kt + o0, &Bg[c0 * 8]);
        gload16(wg + (size_t)(ct * BN + r1c) * K + kt + o1, &Bg[c1 * 8]);
        gload16(wu + (size_t)(ct * BN + r0c) * K + kt + o0, &Bu[c0 * 8]);
        gload16(wu + (size_t)(ct * BN + r1c) * K + kt + o1, &Bu[c1 * 8]);
        __syncthreads();
        s16x8 a[4], bg[4], bu[4];
#pragma unroll
        for (int m = 0; m < 4; m++) a[m] = *(const s16x8*)&As[(wm * 64 + m * 16 + lr) * BK + lk * 8];
#pragma unroll
        for (int n = 0; n < 4; n++) {
            bg[n] = *(const s16x8*)&Bg[(wn * 64 + n * 16 + lr) * BK + lk * 8];
            bu[n] = *(const s16x8*)&Bu[(wn * 64 + n * 16 + lr) * BK + lk * 8];
        }
#pragma unroll
        for (int m = 0; m < 4; m++)
#pragma unroll
            for (int n = 0; n < 4; n++) {
                accg[m][n] = __builtin_amdgcn_mfma_f32_16x16x32_bf16(a[m], bg[n], accg[m][n], 0, 0, 0);
                accu[m][n] = __builtin_amdgcn_mfma_f32_16x16x32_bf16(a[m], bu[n], accu[m][n], 0, 0, 0);
            }
    }
#pragma unroll
    for (int m = 0; m < 4; m++) {
        int row = row0 + wm * 64 + m * 16 + lk * 4;
#pragma unroll
        for (int n = 0; n < 4; n++) {
            int col = ct * BN + wn * 64 + n * 16 + lr;
#pragma unroll
            for (int r = 0; r < 4; r++) {
                float g = accg[m][n][r], u = accu[m][n][r];
                float val = g / (1.f + __expf(-g)) * u;
                hmid[(size_t)(row + r) * IDIM + col] = f2bf(val);
            }
        }
    }
}

// ---------------- GEMM2: out[tok] += hmid @ Wd,  Wd transposed [1024][2048] bf16
__global__ __launch_bounds__(256) void gemm2_k(const ushort_t* __restrict__ A,
                                               const ushort_t* __restrict__ Wd,
                                               const int* __restrict__ pad_off,
                                               const int* __restrict__ order,
                                               float* __restrict__ out) {
    __shared__ ushort_t As[BM * BK], Bs[BN * BK];
    int rt = blockIdx.x, ct = blockIdx.y;
    int row0 = rt * BM;
    const ushort_t* wd = Wd;
    if (pad_off) {
        if (row0 >= pad_off[NEXP]) return;
        int e = 0;
        while (row0 >= pad_off[e + 1]) ++e;
        wd += (size_t)e * HDIM * IDIM;
    }
    const int tid = threadIdx.x, l = tid & 63, wid = tid >> 6;
    const int wm = wid >> 1, wn = wid & 1, lr = l & 15, lk = l >> 4;
    f32x4 acc[4][4] = {};
    const int c0 = tid, c1 = tid + 256;
    const int r0c = c0 >> 2, o0 = (c0 & 3) * 8, r1c = c1 >> 2, o1 = (c1 & 3) * 8;
    const int K = IDIM;
    for (int kt = 0; kt < K; kt += BK) {
        __syncthreads();
        gload16(A + (size_t)(row0 + r0c) * K + kt + o0, &As[c0 * 8]);
        gload16(A + (size_t)(row0 + r1c) * K + kt + o1, &As[c1 * 8]);
        gload16(wd + (size_t)(ct * BN + r0c) * K + kt + o0, &Bs[c0 * 8]);
        gload16(wd + (size_t)(ct * BN + r1c) * K + kt + o1, &Bs[c1 * 8]);
        __syncthreads();
        s16x8 a[4], b[4];
#pragma unroll
        for (int m = 0; m < 4; m++) a[m] = *(const s16x8*)&As[(wm * 64 + m * 16 + lr) * BK + lk * 8];
#pragma unroll
        for (int n = 0; n < 4; n++) b[n] = *(const s16x8*)&Bs[(wn * 64 + n * 16 + lr) * BK + lk * 8];
#pragma unroll
        for (int m = 0; m < 4; m++)
#pragma unroll
            for (int n = 0; n < 4; n++)
                acc[m][n] = __builtin_amdgcn_mfma_f32_16x16x32_bf16(a[m], b[n], acc[m][n], 0, 0, 0);
    }
#pragma unroll
    for (int m = 0; m < 4; m++) {
        int srow = row0 + wm * 64 + m * 16 + lk * 4;
#pragma unroll
        for (int n = 0; n < 4; n++) {
            int col = ct * BN + wn * 64 + n * 16 + lr;
#pragma unroll
            for (int r = 0; r < 4; r++) {
                int rr = srow + r;
                int tok = order ? order[rr] : rr;
                if (tok >= 0) atomicAdd(&out[(size_t)tok * HDIM + col], acc[m][n][r]);
            }
        }
    }
}

extern "C" void kernel_launch(void* const* d_in, const int* in_sizes, int n_in,
                              void* d_out, int out_size, void* d_ws, size_t ws_size,
                              hipStream_t stream) {
    const float* hs = (const float*)d_in[0];
    const float* lnw = (const float*)d_in[1];
    const float* lnb = (const float*)d_in[2];
    const float* rw = (const float*)d_in[3];
    const float* gw = (const float*)d_in[4];
    const float* uw = (const float*)d_in[5];
    const float* dw = (const float*)d_in[6];
    const float* shg = (const float*)d_in[7];
    const float* shu = (const float*)d_in[8];
    const float* shd = (const float*)d_in[9];
    float* out = (float*)d_out;

    char* p = (char*)d_ws;
    auto alloc = [&](size_t bytes) {
        void* r = (void*)p;
        p += (bytes + 255) & ~(size_t)255;
        return r;
    };
    ushort_t* normed = (ushort_t*)alloc((size_t)T_TOK * HDIM * 2);
    ushort_t* xs = (ushort_t*)alloc((size_t)RPAD * HDIM * 2);
    ushort_t* hmid = (ushort_t*)alloc((size_t)RPAD * IDIM * 2);
    ushort_t* gwt = (ushort_t*)alloc((size_t)NEXP * IDIM * HDIM * 2);
    ushort_t* uwt = (ushort_t*)alloc((size_t)NEXP * IDIM * HDIM * 2);
    ushort_t* dwt = (ushort_t*)alloc((size_t)NEXP * HDIM * IDIM * 2);
    ushort_t* shgt = (ushort_t*)alloc((size_t)IDIM * HDIM * 2);
    ushort_t* shut = (ushort_t*)alloc((size_t)IDIM * HDIM * 2);
    ushort_t* shdt = (ushort_t*)alloc((size_t)HDIM * IDIM * 2);
    int* cnt = (int*)alloc(NEXP * 4);
    int* pad_off = (int*)alloc((NEXP + 1) * 4);
    int* fill = (int*)alloc(NEXP * 4);
    int* top_idx = (int*)alloc(T_TOK * 4);
    float* top_sc = (float*)alloc(T_TOK * 4);
    int* order = (int*)alloc(RPAD * 4);

    hipMemsetAsync(cnt, 0, NEXP * 4, stream);
    hipMemsetAsync(order, 0xFF, RPAD * 4, stream);
    hipMemsetAsync(xs, 0, (size_t)RPAD * HDIM * 2, stream);

    dim3 tb(32, 8);
    tcvt<<<dim3(IDIM / 32, HDIM / 32, NEXP), tb, 0, stream>>>(gw, gwt, HDIM, IDIM);
    tcvt<<<dim3(IDIM / 32, HDIM / 32, NEXP), tb, 0, stream>>>(uw, uwt, HDIM, IDIM);
    tcvt<<<dim3(HDIM / 32, IDIM / 32, NEXP), tb, 0, stream>>>(dw, dwt, IDIM, HDIM);
    tcvt<<<dim3(IDIM / 32, HDIM / 32, 1), tb, 0, stream>>>(shg, shgt, HDIM, IDIM);
    tcvt<<<dim3(IDIM / 32, HDIM / 32, 1), tb, 0, stream>>>(shu, shut, HDIM, IDIM);
    tcvt<<<dim3(HDIM / 32, IDIM / 32, 1), tb, 0, stream>>>(shd, shdt, IDIM, HDIM);

    ln_router<<<T_TOK, 256, 0, stream>>>(hs, lnw, lnb, rw, normed, top_idx, top_sc, cnt);
    scan_k<<<1, 64, 0, stream>>>(cnt, pad_off, fill);
    scatter_k<<<T_TOK, 256, 0, stream>>>(normed, top_idx, top_sc, pad_off, fill, order, xs);

    hipMemcpyAsync(out, hs, (size_t)T_TOK * HDIM * 4, hipMemcpyDeviceToDevice, stream);

    // routed experts
    gemm1_k<<<dim3(RPAD / BM, IDIM / BN), 256, 0, stream>>>(xs, gwt, uwt, pad_off, hmid);
    gemm2_k<<<dim3(RPAD / BM, HDIM / BN), 256, 0, stream>>>(hmid, dwt, pad_off, order, out);
    // shared expert (dense over all tokens)
    gemm1_k<<<dim3(T_TOK / BM, IDIM / BN), 256, 0, stream>>>(normed, shgt, shut, nullptr, hmid);
    gemm2_k<<<dim3(T_TOK / BM, HDIM / BN), 256, 0, stream>>>(hmid, shdt, nullptr, nullptr, out);
}

// Round 2
// 643.934 us; speedup vs baseline: 1.3069x; 1.3069x over previous
//
#include <hip/hip_runtime.h>

typedef unsigned short ushort_t;
typedef unsigned int uint_t;

#define T_TOK 8192
#define HDIM 1024
#define IDIM 2048
#define NEXP 8
#define RPAD (T_TOK + NEXP * 128)   // 9216 worst-case padded routed rows (pad to 128)

using f32x4 = __attribute__((ext_vector_type(4))) float;
using s16x8 = __attribute__((ext_vector_type(8))) short;

#define SBAR() do { __builtin_amdgcn_s_barrier(); __builtin_amdgcn_sched_barrier(0); asm volatile("" ::: "memory"); } while (0)
#define VMCNT(n) asm volatile("s_waitcnt vmcnt(" #n ")" ::: "memory")

__device__ __forceinline__ float b2f(ushort_t h) {
    return __uint_as_float(((uint_t)h) << 16);
}
__device__ __forceinline__ ushort_t f2bf(float f) {
    uint_t u = __float_as_uint(f);
    uint_t r = (u + 0x7FFFu + ((u >> 16) & 1u)) >> 16;
    return (ushort_t)r;
}

__device__ __forceinline__ void gload16(const void* g, void* l) {
    __builtin_amdgcn_global_load_lds(
        (const __attribute__((address_space(1))) void*)g,
        (__attribute__((address_space(3))) void*)l, 16, 0, 0);
}

// ---------------- transpose + fp32->bf16 convert: src[b][R][C] f32 -> dst[b][C][R] bf16
__global__ void tcvt(const float* __restrict__ src, ushort_t* __restrict__ dst, int R, int C) {
    __shared__ float tile[32][33];
    size_t bo = (size_t)blockIdx.z * R * C;
    int c0 = blockIdx.x * 32, r0 = blockIdx.y * 32;
    int tx = threadIdx.x, ty = threadIdx.y;
#pragma unroll
    for (int i = 0; i < 32; i += 8)
        tile[ty + i][tx] = src[bo + (size_t)(r0 + ty + i) * C + c0 + tx];
    __syncthreads();
#pragma unroll
    for (int i = 0; i < 32; i += 8)
        dst[bo + (size_t)(c0 + ty + i) * R + r0 + tx] = f2bf(tile[tx][ty + i]);
}

// ---------------- layernorm + router (block per token)
__global__ void ln_router(const float* __restrict__ x, const float* __restrict__ lnw,
                          const float* __restrict__ lnb, const float* __restrict__ rw,
                          ushort_t* __restrict__ normed, int* __restrict__ top_idx,
                          float* __restrict__ top_score, int* __restrict__ cnt) {
    int t = blockIdx.x, tid = threadIdx.x;
    const float* xr = x + (size_t)t * HDIM;
    float v[4];
    float s = 0.f, ss = 0.f;
#pragma unroll
    for (int i = 0; i < 4; i++) {
        v[i] = xr[tid + i * 256];
        s += v[i];
        ss += v[i] * v[i];
    }
#pragma unroll
    for (int o = 32; o; o >>= 1) {
        s += __shfl_down(s, o);
        ss += __shfl_down(ss, o);
    }
    __shared__ float rs_[4], rss_[4], stats[2];
    int wid = tid >> 6, lane = tid & 63;
    if (!lane) { rs_[wid] = s; rss_[wid] = ss; }
    __syncthreads();
    if (!tid) {
        float S = rs_[0] + rs_[1] + rs_[2] + rs_[3];
        float SS = rss_[0] + rss_[1] + rss_[2] + rss_[3];
        float mu = S * (1.f / HDIM);
        float var = SS * (1.f / HDIM) - mu * mu;
        stats[0] = mu;
        stats[1] = rsqrtf(var + 1e-5f);
    }
    __syncthreads();
    float mu = stats[0], rsg = stats[1];
    float lg[8] = {0, 0, 0, 0, 0, 0, 0, 0};
#pragma unroll
    for (int i = 0; i < 4; i++) {
        int h = tid + i * 256;
        float xn = (v[i] - mu) * rsg * lnw[h] + lnb[h];
        normed[(size_t)t * HDIM + h] = f2bf(xn);
        const float* rwh = rw + (size_t)h * NEXP;
#pragma unroll
        for (int e = 0; e < 8; e++) lg[e] += xn * rwh[e];
    }
#pragma unroll
    for (int o = 32; o; o >>= 1)
#pragma unroll
        for (int e = 0; e < 8; e++) lg[e] += __shfl_down(lg[e], o);
    __shared__ float lred[4][8];
    if (!lane)
#pragma unroll
        for (int e = 0; e < 8; e++) lred[wid][e] = lg[e];
    __syncthreads();
    if (!tid) {
        float best = -1e30f;
        int bi = 0;
#pragma unroll
        for (int e = 0; e < 8; e++) {
            float L = lred[0][e] + lred[1][e] + lred[2][e] + lred[3][e];
            if (L > best) { best = L; bi = e; }
        }
        top_idx[t] = bi;
        top_score[t] = 1.f / (1.f + __expf(-best));
        atomicAdd(&cnt[bi], 1);
    }
}

__global__ void scan_k(const int* __restrict__ cnt, int* __restrict__ pad_off,
                       int* __restrict__ fill) {
    if (threadIdx.x == 0) {
        int o = 0;
        for (int e = 0; e < NEXP; e++) {
            pad_off[e] = o;
            o += (cnt[e] + 127) & ~127;
        }
        pad_off[NEXP] = o;
    }
    if (threadIdx.x < NEXP) fill[threadIdx.x] = 0;
}

__global__ void scatter_k(const ushort_t* __restrict__ normed, const int* __restrict__ top_idx,
                          const float* __restrict__ top_score, const int* __restrict__ pad_off,
                          int* __restrict__ fill, int* __restrict__ order,
                          ushort_t* __restrict__ xs) {
    int t = blockIdx.x, tid = threadIdx.x;
    __shared__ int spos;
    if (!tid) {
        int e = top_idx[t];
        int p = pad_off[e] + atomicAdd(&fill[e], 1);
        order[p] = t;
        spos = p;
    }
    __syncthreads();
    int pos = spos;
    float sc = top_score[t];
    const ushort4* src = (const ushort4*)(normed + (size_t)t * HDIM);
    ushort4* dst = (ushort4*)(xs + (size_t)pos * HDIM);
    ushort4 a = src[tid];
    a.x = f2bf(b2f(a.x) * sc);
    a.y = f2bf(b2f(a.y) * sc);
    a.z = f2bf(b2f(a.z) * sc);
    a.w = f2bf(b2f(a.w) * sc);
    dst[tid] = a;
}

// ================= GEMM1: hmid = silu(A@Wg^T)*(A@Wu^T)
// BM=128 rows, BN=128 cols (of BOTH g and u), BK=64. 512 threads, 8 waves (2Mx4N).
// 3-buffer LDS rotation (48KB/buf = A 16K + Bg 16K + Bu 16K), staged 2 tiles ahead.
// Per K-tile: 2 phases (K-halves), 16 MFMA each. Counted vmcnt(6) once per tile.
__global__ __launch_bounds__(512, 2) void gemm1_k(const ushort_t* __restrict__ A,
                                                  const ushort_t* __restrict__ Wg,
                                                  const ushort_t* __restrict__ Wu,
                                                  const int* __restrict__ pad_off,
                                                  ushort_t* __restrict__ hmid, int RT, int CT) {
    __shared__ ushort_t lds[3 * 24576];   // 144 KB
    const int NKT = HDIM / 64;            // 16
    int nwg = RT * CT;
    int bid = blockIdx.x;
    int q = nwg >> 3, r = nwg & 7;
    int xcd = bid & 7, idx = bid >> 3;
    int wg = (xcd < r ? xcd * (q + 1) : r * (q + 1) + (xcd - r) * q) + idx;
    int ct = wg / RT, rt = wg % RT;
    int row0 = rt * 128, col0 = ct * 128;
    const ushort_t* wgp = Wg;
    const ushort_t* wup = Wu;
    if (pad_off) {
        if (row0 >= pad_off[NEXP]) return;
        int e = 0;
        while (row0 >= pad_off[e + 1]) ++e;
        size_t wo = (size_t)e * IDIM * HDIM;
        wgp += wo;
        wup += wo;
    }
    const int tid = threadIdx.x, l = tid & 63, w = tid >> 6;
    const int wm = w >> 2, wn = w & 3;
    const int lr = l & 15, lg = l >> 4, l7 = l & 7;
    // staging: thread covers row sr (within 64-row block), physical granule sp
    const int sr = w * 8 + (l >> 3), sp = l & 7;
    const int scol = (sp ^ (sr & 7)) * 8;                // pre-swizzled source col
    const int dloc = (w * 64 + l) * 8;                   // elems within 4096-elem round
    const ushort_t* gsrc[6];
    gsrc[0] = A + (size_t)(row0 + sr) * HDIM + scol;
    gsrc[1] = A + (size_t)(row0 + 64 + sr) * HDIM + scol;
    gsrc[2] = wgp + (size_t)(col0 + sr) * HDIM + scol;
    gsrc[3] = wgp + (size_t)(col0 + 64 + sr) * HDIM + scol;
    gsrc[4] = wup + (size_t)(col0 + sr) * HDIM + scol;
    gsrc[5] = wup + (size_t)(col0 + 64 + sr) * HDIM + scol;
    const int dreg[6] = {0, 4096, 8192, 12288, 16384, 20480};

    f32x4 accg[4][2] = {};
    f32x4 accu[4][2] = {};

    // prologue: tile 0 -> buf0, tile 1 -> buf1
#pragma unroll
    for (int j = 0; j < 6; ++j) gload16(gsrc[j], &lds[dreg[j] + dloc]);
#pragma unroll
    for (int j = 0; j < 6; ++j) gload16(gsrc[j] + 64, &lds[24576 + dreg[j] + dloc]);
    VMCNT(6);
    SBAR();

    int b = 0;
    for (int kt = 0; kt < NKT; ++kt) {
        int b2 = b + 2; if (b2 >= 3) b2 -= 3;
        const int be = b * 24576, b2e = b2 * 24576;
        int kk2 = (kt + 2 < NKT ? kt + 2 : NKT - 1) * 64;
        // ---- phase 0 (K-slice 0..31)
#pragma unroll
        for (int j = 0; j < 3; ++j) gload16(gsrc[j] + kk2, &lds[b2e + dreg[j] + dloc]);
        {
            int gran = ((0 + lg) ^ l7) * 8;
            s16x8 a[4], bg[2], bu[2];
#pragma unroll
            for (int m = 0; m < 4; ++m) a[m] = *(const s16x8*)&lds[be + (wm * 64 + m * 16 + lr) * 64 + gran];
#pragma unroll
            for (int n = 0; n < 2; ++n) {
                bg[n] = *(const s16x8*)&lds[be + 8192 + (wn * 32 + n * 16 + lr) * 64 + gran];
                bu[n] = *(const s16x8*)&lds[be + 16384 + (wn * 32 + n * 16 + lr) * 64 + gran];
            }
            SBAR();
            __builtin_amdgcn_s_setprio(1);
#pragma unroll
            for (int m = 0; m < 4; ++m)
#pragma unroll
                for (int n = 0; n < 2; ++n) {
                    accg[m][n] = __builtin_amdgcn_mfma_f32_16x16x32_bf16(a[m], bg[n], accg[m][n], 0, 0, 0);
                    accu[m][n] = __builtin_amdgcn_mfma_f32_16x16x32_bf16(a[m], bu[n], accu[m][n], 0, 0, 0);
                }
            __builtin_amdgcn_s_setprio(0);
            SBAR();
        }
        // ---- phase 1 (K-slice 32..63)
#pragma unroll
        for (int j = 3; j < 6; ++j) gload16(gsrc[j] + kk2, &lds[b2e + dreg[j] + dloc]);
        {
            int gran = ((4 + lg) ^ l7) * 8;
            s16x8 a[4], bg[2], bu[2];
#pragma unroll
            for (int m = 0; m < 4; ++m) a[m] = *(const s16x8*)&lds[be + (wm * 64 + m * 16 + lr) * 64 + gran];
#pragma unroll
            for (int n = 0; n < 2; ++n) {
                bg[n] = *(const s16x8*)&lds[be + 8192 + (wn * 32 + n * 16 + lr) * 64 + gran];
                bu[n] = *(const s16x8*)&lds[be + 16384 + (wn * 32 + n * 16 + lr) * 64 + gran];
            }
            VMCNT(6);
            SBAR();
            __builtin_amdgcn_s_setprio(1);
#pragma unroll
            for (int m = 0; m < 4; ++m)
#pragma unroll
                for (int n = 0; n < 2; ++n) {
                    accg[m][n] = __builtin_amdgcn_mfma_f32_16x16x32_bf16(a[m], bg[n], accg[m][n], 0, 0, 0);
                    accu[m][n] = __builtin_amdgcn_mfma_f32_16x16x32_bf16(a[m], bu[n], accu[m][n], 0, 0, 0);
                }
            __builtin_amdgcn_s_setprio(0);
            SBAR();
        }
        b = b + 1; if (b >= 3) b -= 3;
    }
    // epilogue: silu(g)*u -> bf16
#pragma unroll
    for (int m = 0; m < 4; ++m) {
        int row = row0 + wm * 64 + m * 16 + lg * 4;
#pragma unroll
        for (int n = 0; n < 2; ++n) {
            int col = col0 + wn * 32 + n * 16 + lr;
#pragma unroll
            for (int rr = 0; rr < 4; ++rr) {
                float g = accg[m][n][rr], u = accu[m][n][rr];
                float val = g / (1.f + __expf(-g)) * u;
                hmid[(size_t)(row + rr) * IDIM + col] = f2bf(val);
            }
        }
    }
}

// ================= GEMM2: out[tok] += hmid @ Wd^T. BM=128, BN=128, BK=64.
// 3-buffer rotation (32KB/buf), 1 phase/tile (16 MFMA), counted vmcnt(4).
__global__ __launch_bounds__(512, 2) void gemm2_k(const ushort_t* __restrict__ A,
                                                  const ushort_t* __restrict__ Wd,
                                                  const int* __restrict__ pad_off,
                                                  const int* __restrict__ order,
                                                  float* __restrict__ out, int RT, int CT) {
    __shared__ ushort_t lds[3 * 16384];   // 96 KB
    const int NKT = IDIM / 64;            // 32
    int nwg = RT * CT;
    int bid = blockIdx.x;
    int q = nwg >> 3, r = nwg & 7;
    int xcd = bid & 7, idx = bid >> 3;
    int wg = (xcd < r ? xcd * (q + 1) : r * (q + 1) + (xcd - r) * q) + idx;
    int ct = wg / RT, rt = wg % RT;
    int row0 = rt * 128, col0 = ct * 128;
    const ushort_t* wd = Wd;
    if (pad_off) {
        if (row0 >= pad_off[NEXP]) return;
        int e = 0;
        while (row0 >= pad_off[e + 1]) ++e;
        wd += (size_t)e * HDIM * IDIM;
    }
    const int tid = threadIdx.x, l = tid & 63, w = tid >> 6;
    const int wm = w >> 2, wn = w & 3;
    const int lr = l & 15, lg = l >> 4, l7 = l & 7;
    const int sr = w * 8 + (l >> 3), sp = l & 7;
    const int scol = (sp ^ (sr & 7)) * 8;
    const int dloc = (w * 64 + l) * 8;
    const ushort_t* gsrc[4];
    gsrc[0] = A + (size_t)(row0 + sr) * IDIM + scol;
    gsrc[1] = A + (size_t)(row0 + 64 + sr) * IDIM + scol;
    gsrc[2] = wd + (size_t)(col0 + sr) * IDIM + scol;
    gsrc[3] = wd + (size_t)(col0 + 64 + sr) * IDIM + scol;
    const int dreg[4] = {0, 4096, 8192, 12288};

    f32x4 acc[4][2] = {};

#pragma unroll
    for (int j = 0; j < 4; ++j) gload16(gsrc[j], &lds[dreg[j] + dloc]);
#pragma unroll
    for (int j = 0; j < 4; ++j) gload16(gsrc[j] + 64, &lds[16384 + dreg[j] + dloc]);
    VMCNT(4);
    SBAR();

    int b = 0;
    for (int kt = 0; kt < NKT; ++kt) {
        int b2 = b + 2; if (b2 >= 3) b2 -= 3;
        const int be = b * 16384, b2e = b2 * 16384;
        int kk2 = (kt + 2 < NKT ? kt + 2 : NKT - 1) * 64;
#pragma unroll
        for (int j = 0; j < 4; ++j) gload16(gsrc[j] + kk2, &lds[b2e + dreg[j] + dloc]);
        s16x8 a[2][4], bb[2][2];
#pragma unroll
        for (int k = 0; k < 2; ++k) {
            int gran = ((k * 4 + lg) ^ l7) * 8;
#pragma unroll
            for (int m = 0; m < 4; ++m) a[k][m] = *(const s16x8*)&lds[be + (wm * 64 + m * 16 + lr) * 64 + gran];
#pragma unroll
            for (int n = 0; n < 2; ++n) bb[k][n] = *(const s16x8*)&lds[be + 8192 + (wn * 32 + n * 16 + lr) * 64 + gran];
        }
        VMCNT(4);
        SBAR();
        __builtin_amdgcn_s_setprio(1);
#pragma unroll
        for (int k = 0; k < 2; ++k)
#pragma unroll
            for (int m = 0; m < 4; ++m)
#pragma unroll
                for (int n = 0; n < 2; ++n)
                    acc[m][n] = __builtin_amdgcn_mfma_f32_16x16x32_bf16(a[k][m], bb[k][n], acc[m][n], 0, 0, 0);
        __builtin_amdgcn_s_setprio(0);
        SBAR();
        b = b + 1; if (b >= 3) b -= 3;
    }
#pragma unroll
    for (int m = 0; m < 4; ++m) {
        int srow = row0 + wm * 64 + m * 16 + lg * 4;
#pragma unroll
        for (int n = 0; n < 2; ++n) {
            int col = col0 + wn * 32 + n * 16 + lr;
#pragma unroll
            for (int rr = 0; rr < 4; ++rr) {
                int rw_ = srow + rr;
                int tok = order ? order[rw_] : rw_;
                if (tok >= 0) atomicAdd(&out[(size_t)tok * HDIM + col], acc[m][n][rr]);
            }
        }
    }
}

extern "C" void kernel_launch(void* const* d_in, const int* in_sizes, int n_in,
                              void* d_out, int out_size, void* d_ws, size_t ws_size,
                              hipStream_t stream) {
    const float* hs = (const float*)d_in[0];
    const float* lnw = (const float*)d_in[1];
    const float* lnb = (const float*)d_in[2];
    const float* rw = (const float*)d_in[3];
    const float* gw = (const float*)d_in[4];
    const float* uw = (const float*)d_in[5];
    const float* dw = (const float*)d_in[6];
    const float* shg = (const float*)d_in[7];
    const float* shu = (const float*)d_in[8];
    const float* shd = (const float*)d_in[9];
    float* out = (float*)d_out;

    char* p = (char*)d_ws;
    auto alloc = [&](size_t bytes) {
        void* r = (void*)p;
        p += (bytes + 255) & ~(size_t)255;
        return r;
    };
    ushort_t* normed = (ushort_t*)alloc((size_t)T_TOK * HDIM * 2);
    ushort_t* xs = (ushort_t*)alloc((size_t)RPAD * HDIM * 2);
    ushort_t* hmid = (ushort_t*)alloc((size_t)RPAD * IDIM * 2);
    ushort_t* gwt = (ushort_t*)alloc((size_t)NEXP * IDIM * HDIM * 2);
    ushort_t* uwt = (ushort_t*)alloc((size_t)NEXP * IDIM * HDIM * 2);
    ushort_t* dwt = (ushort_t*)alloc((size_t)NEXP * HDIM * IDIM * 2);
    ushort_t* shgt = (ushort_t*)alloc((size_t)IDIM * HDIM * 2);
    ushort_t* shut = (ushort_t*)alloc((size_t)IDIM * HDIM * 2);
    ushort_t* shdt = (ushort_t*)alloc((size_t)HDIM * IDIM * 2);
    int* cnt = (int*)alloc(NEXP * 4);
    int* pad_off = (int*)alloc((NEXP + 1) * 4);
    int* fill = (int*)alloc(NEXP * 4);
    int* top_idx = (int*)alloc(T_TOK * 4);
    float* top_sc = (float*)alloc(T_TOK * 4);
    int* order = (int*)alloc(RPAD * 4);

    hipMemsetAsync(cnt, 0, NEXP * 4, stream);
    hipMemsetAsync(order, 0xFF, RPAD * 4, stream);
    hipMemsetAsync(xs, 0, (size_t)RPAD * HDIM * 2, stream);

    dim3 tb(32, 8);
    tcvt<<<dim3(IDIM / 32, HDIM / 32, NEXP), tb, 0, stream>>>(gw, gwt, HDIM, IDIM);
    tcvt<<<dim3(IDIM / 32, HDIM / 32, NEXP), tb, 0, stream>>>(uw, uwt, HDIM, IDIM);
    tcvt<<<dim3(HDIM / 32, IDIM / 32, NEXP), tb, 0, stream>>>(dw, dwt, IDIM, HDIM);
    tcvt<<<dim3(IDIM / 32, HDIM / 32, 1), tb, 0, stream>>>(shg, shgt, HDIM, IDIM);
    tcvt<<<dim3(IDIM / 32, HDIM / 32, 1), tb, 0, stream>>>(shu, shut, HDIM, IDIM);
    tcvt<<<dim3(HDIM / 32, IDIM / 32, 1), tb, 0, stream>>>(shd, shdt, IDIM, HDIM);

    ln_router<<<T_TOK, 256, 0, stream>>>(hs, lnw, lnb, rw, normed, top_idx, top_sc, cnt);
    scan_k<<<1, 64, 0, stream>>>(cnt, pad_off, fill);
    scatter_k<<<T_TOK, 256, 0, stream>>>(normed, top_idx, top_sc, pad_off, fill, order, xs);

    hipMemcpyAsync(out, hs, (size_t)T_TOK * HDIM * 4, hipMemcpyDeviceToDevice, stream);

    // routed: gemm1 -> hmid, gemm2 -> out (atomic)
    {
        int RT = RPAD / 128, CT = IDIM / 128;
        gemm1_k<<<RT * CT, 512, 0, stream>>>(xs, gwt, uwt, pad_off, hmid, RT, CT);
    }
    {
        int RT = RPAD / 128, CT = HDIM / 128;
        gemm2_k<<<RT * CT, 512, 0, stream>>>(hmid, dwt, pad_off, order, out, RT, CT);
    }
    // shared expert (dense over all tokens), reuses hmid
    {
        int RT = T_TOK / 128, CT = IDIM / 128;
        gemm1_k<<<RT * CT, 512, 0, stream>>>(normed, shgt, shut, nullptr, hmid, RT, CT);
    }
    {
        int RT = T_TOK / 128, CT = HDIM / 128;
        gemm2_k<<<RT * CT, 512, 0, stream>>>(hmid, shdt, nullptr, nullptr, out, RT, CT);
    }
}

// Round 4
// 603.495 us; speedup vs baseline: 1.3945x; 1.0670x over previous
//
#include <hip/hip_runtime.h>

typedef unsigned short ushort_t;
typedef unsigned int uint_t;

#define T_TOK 8192
#define HDIM 1024
#define IDIM 2048
#define NEXP 8
#define RPAD_MAX 10240                 // 8192 + 8*256 worst-case padded routed rows
#define TOTROWS (RPAD_MAX + T_TOK)     // 18432

using f32x4 = __attribute__((ext_vector_type(4))) float;
using s16x8 = __attribute__((ext_vector_type(8))) short;

#define SBAR() do { asm volatile("" ::: "memory"); __builtin_amdgcn_s_barrier(); asm volatile("" ::: "memory"); } while (0)
#define VMW(n) asm volatile("s_waitcnt vmcnt(" #n ")" ::: "memory")
#define LGKM0() do { asm volatile("s_waitcnt lgkmcnt(0)" ::: "memory"); __builtin_amdgcn_sched_barrier(0); } while (0)

__device__ __forceinline__ float b2f(ushort_t h) {
    return __uint_as_float(((uint_t)h) << 16);
}
__device__ __forceinline__ ushort_t f2bf(float f) {
    uint_t u = __float_as_uint(f);
    uint_t r = (u + 0x7FFFu + ((u >> 16) & 1u)) >> 16;
    return (ushort_t)r;
}
__device__ __forceinline__ void gload16(const void* g, void* l) {
    __builtin_amdgcn_global_load_lds(
        (const __attribute__((address_space(1))) void*)g,
        (__attribute__((address_space(3))) void*)l, 16, 0, 0);
}
// decode staging granule: LDS granule gi (paired-row layout, XOR swizzle) -> (row, k-granule)
__device__ __forceinline__ void gdec(int gi, int& r, int& kg) {
    int prow = gi >> 3, v = (gi & 7) ^ (prow & 7);
    r = 2 * prow + (v >> 2);
    kg = v & 3;
}

// ---------------- merged transpose+convert: gate & up (R=HDIM, C=IDIM)
__global__ void tcvt_gu(const float* __restrict__ gw, const float* __restrict__ shg,
                        const float* __restrict__ uw, const float* __restrict__ shu,
                        ushort_t* __restrict__ gwt, ushort_t* __restrict__ uwt) {
    __shared__ float tile[32][33];
    int z = blockIdx.z, zz = z % 9;
    const float* src;
    ushort_t* dst;
    if (z < 9) {
        src = zz < 8 ? gw + (size_t)zz * HDIM * IDIM : shg;
        dst = gwt + (size_t)zz * IDIM * HDIM;
    } else {
        src = zz < 8 ? uw + (size_t)zz * HDIM * IDIM : shu;
        dst = uwt + (size_t)zz * IDIM * HDIM;
    }
    int c0 = blockIdx.x * 32, r0 = blockIdx.y * 32;
    int tx = threadIdx.x, ty = threadIdx.y;
#pragma unroll
    for (int i = 0; i < 32; i += 8)
        tile[ty + i][tx] = src[(size_t)(r0 + ty + i) * IDIM + c0 + tx];
    __syncthreads();
#pragma unroll
    for (int i = 0; i < 32; i += 8)
        dst[(size_t)(c0 + ty + i) * HDIM + r0 + tx] = f2bf(tile[tx][ty + i]);
}
// down (R=IDIM, C=HDIM)
__global__ void tcvt_d(const float* __restrict__ dw, const float* __restrict__ shd,
                       ushort_t* __restrict__ dwt) {
    __shared__ float tile[32][33];
    int z = blockIdx.z;
    const float* src = z < 8 ? dw + (size_t)z * IDIM * HDIM : shd;
    ushort_t* dst = dwt + (size_t)z * HDIM * IDIM;
    int c0 = blockIdx.x * 32, r0 = blockIdx.y * 32;
    int tx = threadIdx.x, ty = threadIdx.y;
#pragma unroll
    for (int i = 0; i < 32; i += 8)
        tile[ty + i][tx] = src[(size_t)(r0 + ty + i) * HDIM + c0 + tx];
    __syncthreads();
#pragma unroll
    for (int i = 0; i < 32; i += 8)
        dst[(size_t)(c0 + ty + i) * IDIM + r0 + tx] = f2bf(tile[tx][ty + i]);
}

// ---------------- layernorm + router
__global__ void ln_router(const float* __restrict__ x, const float* __restrict__ lnw,
                          const float* __restrict__ lnb, const float* __restrict__ rw,
                          ushort_t* __restrict__ normed, int* __restrict__ top_idx,
                          float* __restrict__ top_score, int* __restrict__ cnt) {
    int t = blockIdx.x, tid = threadIdx.x;
    const float* xr = x + (size_t)t * HDIM;
    float v[4];
    float s = 0.f, ss = 0.f;
#pragma unroll
    for (int i = 0; i < 4; i++) {
        v[i] = xr[tid + i * 256];
        s += v[i];
        ss += v[i] * v[i];
    }
#pragma unroll
    for (int o = 32; o; o >>= 1) {
        s += __shfl_down(s, o);
        ss += __shfl_down(ss, o);
    }
    __shared__ float rs_[4], rss_[4], stats[2];
    int wid = tid >> 6, lane = tid & 63;
    if (!lane) { rs_[wid] = s; rss_[wid] = ss; }
    __syncthreads();
    if (!tid) {
        float S = rs_[0] + rs_[1] + rs_[2] + rs_[3];
        float SS = rss_[0] + rss_[1] + rss_[2] + rss_[3];
        float mu = S * (1.f / HDIM);
        float var = SS * (1.f / HDIM) - mu * mu;
        stats[0] = mu;
        stats[1] = rsqrtf(var + 1e-5f);
    }
    __syncthreads();
    float mu = stats[0], rsg = stats[1];
    float lg[8] = {0, 0, 0, 0, 0, 0, 0, 0};
#pragma unroll
    for (int i = 0; i < 4; i++) {
        int h = tid + i * 256;
        float xn = (v[i] - mu) * rsg * lnw[h] + lnb[h];
        normed[(size_t)t * HDIM + h] = f2bf(xn);
        const float* rwh = rw + (size_t)h * NEXP;
#pragma unroll
        for (int e = 0; e < 8; e++) lg[e] += xn * rwh[e];
    }
#pragma unroll
    for (int o = 32; o; o >>= 1)
#pragma unroll
        for (int e = 0; e < 8; e++) lg[e] += __shfl_down(lg[e], o);
    __shared__ float lred[4][8];
    if (!lane)
#pragma unroll
        for (int e = 0; e < 8; e++) lred[wid][e] = lg[e];
    __syncthreads();
    if (!tid) {
        float best = -1e30f;
        int bi = 0;
#pragma unroll
        for (int e = 0; e < 8; e++) {
            float L = lred[0][e] + lred[1][e] + lred[2][e] + lred[3][e];
            if (L > best) { best = L; bi = e; }
        }
        top_idx[t] = bi;
        top_score[t] = 1.f / (1.f + __expf(-best));
        atomicAdd(&cnt[bi], 1);
    }
}

__global__ void scan_k(const int* __restrict__ cnt, int* __restrict__ pad_off,
                       int* __restrict__ fill) {
    if (threadIdx.x == 0) {
        int o = 0;
        for (int e = 0; e < NEXP; e++) {
            pad_off[e] = o;
            o += (cnt[e] + 255) & ~255;
        }
        pad_off[NEXP] = o;
    }
    if (threadIdx.x < NEXP) fill[threadIdx.x] = 0;
}

__global__ void scatter_k(const ushort_t* __restrict__ normed, const int* __restrict__ top_idx,
                          const float* __restrict__ top_score, const int* __restrict__ pad_off,
                          int* __restrict__ fill, int* __restrict__ order,
                          ushort_t* __restrict__ xs) {
    int t = blockIdx.x, tid = threadIdx.x;
    __shared__ int spos;
    if (!tid) {
        int e = top_idx[t];
        int p = pad_off[e] + atomicAdd(&fill[e], 1);
        order[p] = t;
        spos = p;
    }
    __syncthreads();
    int pos = spos;
    float sc = top_score[t];
    const ushort4* src = (const ushort4*)(normed + (size_t)t * HDIM);
    ushort4* dst = (ushort4*)(xs + (size_t)pos * HDIM);
    ushort4 a = src[tid];
    a.x = f2bf(b2f(a.x) * sc);
    a.y = f2bf(b2f(a.y) * sc);
    a.z = f2bf(b2f(a.z) * sc);
    a.w = f2bf(b2f(a.w) * sc);
    dst[tid] = a;
}

// ================= GEMM1 (fused routed+shared): hmid = silu(X@Wg^T)*(X@Wu^T)
// BM=256, BN=128(g)+128(u), K-half ring of 4 x 32KB LDS buffers. 8 waves 2Mx4N.
__global__ __launch_bounds__(512, 2) void gemm1_k(
    const ushort_t* __restrict__ X, const ushort_t* __restrict__ Wg,
    const ushort_t* __restrict__ Wu, const int* __restrict__ pad_off,
    ushort_t* __restrict__ hmid) {
    __shared__ __align__(16) ushort_t lds[4 * 16384];  // 128 KiB
    const int RT = TOTROWS / 256, CT = IDIM / 128;  // 72, 16
    const int NH = HDIM / 32;                        // 32 halves
    int nwg = RT * CT;
    int bid = blockIdx.x;
    int q = nwg >> 3, r = nwg & 7;
    int xcd = bid & 7, idx = bid >> 3;
    int wg = (xcd < r ? xcd * (q + 1) : r * (q + 1) + (xcd - r) * q) + idx;
    int ct = wg / RT, rt = wg % RT;
    int row0 = rt * 256, col0 = ct * 128;
    int e;
    if (row0 >= RPAD_MAX) e = 8;
    else {
        if (row0 >= pad_off[NEXP]) return;
        e = 0;
        while (row0 >= pad_off[e + 1]) ++e;
    }
    const ushort_t* wgp = Wg + (size_t)e * IDIM * HDIM;
    const ushort_t* wup = Wu + (size_t)e * IDIM * HDIM;

    const int tid = threadIdx.x, l = tid & 63, w = tid >> 6;
    const int wm = w >> 2, wn = w & 3;
    const int lr = l & 15, lg4 = l >> 4;

    // staging: 16B-per-lane stride ONLY (global_load_lds writes wave-base + lane*16B)
    int rA0, kA0, rA1, kA1, rB, kB;
    gdec(tid, rA0, kA0);          // granules [0,512)   -> rows 0..127
    gdec(512 + tid, rA1, kA1);    // granules [512,1024) -> rows 128..255
    gdec(tid, rB, kB);
    const ushort_t* srcA0 = X + (size_t)(row0 + rA0) * HDIM + kA0 * 8;
    const ushort_t* srcA1 = X + (size_t)(row0 + rA1) * HDIM + kA1 * 8;
    const ushort_t* srcBg = wgp + (size_t)(col0 + rB) * HDIM + kB * 8;
    const ushort_t* srcBu = wup + (size_t)(col0 + rB) * HDIM + kB * 8;
    const int dA0 = tid * 8, dA1 = (512 + tid) * 8, dB = tid * 8;

    // fragment read constants
    const int s_slot = (((l & 1) << 2) | lg4) ^ ((l >> 1) & 7);
    const int aoff = (wm * 64 + (lr >> 1)) * 64 + s_slot * 8;
    const int boff = (wn * 16 + (lr >> 1)) * 64 + s_slot * 8;

    f32x4 accg[8][2] = {};
    f32x4 accu[8][2] = {};

#define G1_STAGE(h) do { int ko = (h) * 32; int hb_ = ((h) & 3) * 16384;       \
        gload16(srcA0 + ko, &lds[hb_ + dA0]);                                  \
        gload16(srcA1 + ko, &lds[hb_ + dA1]);                                  \
        gload16(srcBg + ko, &lds[hb_ + 8192 + dB]);                            \
        gload16(srcBu + ko, &lds[hb_ + 12288 + dB]); } while (0)

#define G1_BODY(h, VMWAIT, DOSTAGE) do {                                       \
        const int hb = ((h) & 3) * 16384;                                      \
        VMWAIT; SBAR();                                                        \
        if (DOSTAGE) G1_STAGE((h) + 3);                                        \
        s16x8 a0 = *(const s16x8*)&lds[hb + aoff];                             \
        s16x8 a1 = *(const s16x8*)&lds[hb + aoff + 512];                       \
        s16x8 a2 = *(const s16x8*)&lds[hb + aoff + 1024];                      \
        s16x8 a3 = *(const s16x8*)&lds[hb + aoff + 1536];                      \
        s16x8 bg0 = *(const s16x8*)&lds[hb + 8192 + boff];                     \
        s16x8 bg1 = *(const s16x8*)&lds[hb + 8192 + boff + 512];               \
        s16x8 bu0 = *(const s16x8*)&lds[hb + 12288 + boff];                    \
        s16x8 bu1 = *(const s16x8*)&lds[hb + 12288 + boff + 512];              \
        LGKM0();                                                               \
        __builtin_amdgcn_s_setprio(1);                                         \
        accg[0][0] = __builtin_amdgcn_mfma_f32_16x16x32_bf16(a0, bg0, accg[0][0], 0, 0, 0); \
        accg[0][1] = __builtin_amdgcn_mfma_f32_16x16x32_bf16(a0, bg1, accg[0][1], 0, 0, 0); \
        accu[0][0] = __builtin_amdgcn_mfma_f32_16x16x32_bf16(a0, bu0, accu[0][0], 0, 0, 0); \
        accu[0][1] = __builtin_amdgcn_mfma_f32_16x16x32_bf16(a0, bu1, accu[0][1], 0, 0, 0); \
        accg[1][0] = __builtin_amdgcn_mfma_f32_16x16x32_bf16(a1, bg0, accg[1][0], 0, 0, 0); \
        accg[1][1] = __builtin_amdgcn_mfma_f32_16x16x32_bf16(a1, bg1, accg[1][1], 0, 0, 0); \
        accu[1][0] = __builtin_amdgcn_mfma_f32_16x16x32_bf16(a1, bu0, accu[1][0], 0, 0, 0); \
        accu[1][1] = __builtin_amdgcn_mfma_f32_16x16x32_bf16(a1, bu1, accu[1][1], 0, 0, 0); \
        accg[2][0] = __builtin_amdgcn_mfma_f32_16x16x32_bf16(a2, bg0, accg[2][0], 0, 0, 0); \
        accg[2][1] = __builtin_amdgcn_mfma_f32_16x16x32_bf16(a2, bg1, accg[2][1], 0, 0, 0); \
        accu[2][0] = __builtin_amdgcn_mfma_f32_16x16x32_bf16(a2, bu0, accu[2][0], 0, 0, 0); \
        accu[2][1] = __builtin_amdgcn_mfma_f32_16x16x32_bf16(a2, bu1, accu[2][1], 0, 0, 0); \
        accg[3][0] = __builtin_amdgcn_mfma_f32_16x16x32_bf16(a3, bg0, accg[3][0], 0, 0, 0); \
        accg[3][1] = __builtin_amdgcn_mfma_f32_16x16x32_bf16(a3, bg1, accg[3][1], 0, 0, 0); \
        accu[3][0] = __builtin_amdgcn_mfma_f32_16x16x32_bf16(a3, bu0, accu[3][0], 0, 0, 0); \
        accu[3][1] = __builtin_amdgcn_mfma_f32_16x16x32_bf16(a3, bu1, accu[3][1], 0, 0, 0); \
        __builtin_amdgcn_s_setprio(0);                                         \
        SBAR();                                                                \
        a0 = *(const s16x8*)&lds[hb + aoff + 2048];                            \
        a1 = *(const s16x8*)&lds[hb + aoff + 2560];                            \
        a2 = *(const s16x8*)&lds[hb + aoff + 3072];                            \
        a3 = *(const s16x8*)&lds[hb + aoff + 3584];                            \
        LGKM0();                                                               \
        __builtin_amdgcn_s_setprio(1);                                         \
        accg[4][0] = __builtin_amdgcn_mfma_f32_16x16x32_bf16(a0, bg0, accg[4][0], 0, 0, 0); \
        accg[4][1] = __builtin_amdgcn_mfma_f32_16x16x32_bf16(a0, bg1, accg[4][1], 0, 0, 0); \
        accu[4][0] = __builtin_amdgcn_mfma_f32_16x16x32_bf16(a0, bu0, accu[4][0], 0, 0, 0); \
        accu[4][1] = __builtin_amdgcn_mfma_f32_16x16x32_bf16(a0, bu1, accu[4][1], 0, 0, 0); \
        accg[5][0] = __builtin_amdgcn_mfma_f32_16x16x32_bf16(a1, bg0, accg[5][0], 0, 0, 0); \
        accg[5][1] = __builtin_amdgcn_mfma_f32_16x16x32_bf16(a1, bg1, accg[5][1], 0, 0, 0); \
        accu[5][0] = __builtin_amdgcn_mfma_f32_16x16x32_bf16(a1, bu0, accu[5][0], 0, 0, 0); \
        accu[5][1] = __builtin_amdgcn_mfma_f32_16x16x32_bf16(a1, bu1, accu[5][1], 0, 0, 0); \
        accg[6][0] = __builtin_amdgcn_mfma_f32_16x16x32_bf16(a2, bg0, accg[6][0], 0, 0, 0); \
        accg[6][1] = __builtin_amdgcn_mfma_f32_16x16x32_bf16(a2, bg1, accg[6][1], 0, 0, 0); \
        accu[6][0] = __builtin_amdgcn_mfma_f32_16x16x32_bf16(a2, bu0, accu[6][0], 0, 0, 0); \
        accu[6][1] = __builtin_amdgcn_mfma_f32_16x16x32_bf16(a2, bu1, accu[6][1], 0, 0, 0); \
        accg[7][0] = __builtin_amdgcn_mfma_f32_16x16x32_bf16(a3, bg0, accg[7][0], 0, 0, 0); \
        accg[7][1] = __builtin_amdgcn_mfma_f32_16x16x32_bf16(a3, bg1, accg[7][1], 0, 0, 0); \
        accu[7][0] = __builtin_amdgcn_mfma_f32_16x16x32_bf16(a3, bu0, accu[7][0], 0, 0, 0); \
        accu[7][1] = __builtin_amdgcn_mfma_f32_16x16x32_bf16(a3, bu1, accu[7][1], 0, 0, 0); \
        __builtin_amdgcn_s_setprio(0);                                         \
        SBAR();                                                                \
    } while (0)

    G1_STAGE(0);
    G1_STAGE(1);
    G1_STAGE(2);
    for (int h = 0; h < NH - 3; ++h) G1_BODY(h, VMW(8), 1);
    G1_BODY(NH - 3, VMW(8), 0);
    G1_BODY(NH - 2, VMW(4), 0);
    G1_BODY(NH - 1, VMW(0), 0);

#pragma unroll
    for (int mf = 0; mf < 8; ++mf) {
        int row = row0 + wm * 128 + mf * 16 + lg4 * 4;
#pragma unroll
        for (int nf = 0; nf < 2; ++nf) {
            int col = col0 + wn * 32 + nf * 16 + lr;
#pragma unroll
            for (int rr = 0; rr < 4; ++rr) {
                float g = accg[mf][nf][rr], u = accu[mf][nf][rr];
                float val = g / (1.f + __expf(-g)) * u;
                hmid[(size_t)(row + rr) * IDIM + col] = f2bf(val);
            }
        }
    }
#undef G1_STAGE
#undef G1_BODY
}

// ================= GEMM2: out(+)= Hm @ Wd^T. BM=256, BN=128, 4x24KB ring.
// SHARED=1: out = hs + acc (plain store). SHARED=0: out += acc (plain RMW, order lookup).
template <int SHARED>
__global__ __launch_bounds__(512, 2) void gemm2_k(
    const ushort_t* __restrict__ Hm, const ushort_t* __restrict__ Wd,
    const int* __restrict__ pad_off, const int* __restrict__ order,
    const float* __restrict__ hs, float* __restrict__ out, int RT) {
    __shared__ __align__(16) ushort_t lds[4 * 12288];  // 96 KiB
    const int CT = HDIM / 128;           // 8
    const int NH = IDIM / 32;            // 64 halves
    int nwg = RT * CT;
    int bid = blockIdx.x;
    int q = nwg >> 3, r = nwg & 7;
    int xcd = bid & 7, idx = bid >> 3;
    int wg = (xcd < r ? xcd * (q + 1) : r * (q + 1) + (xcd - r) * q) + idx;
    int ct = wg / RT, rt = wg % RT;
    int row0 = rt * 256, col0 = ct * 128;
    const ushort_t* wdp;
    if (SHARED) {
        wdp = Wd + (size_t)8 * HDIM * IDIM;
    } else {
        if (row0 >= pad_off[NEXP]) return;
        int e = 0;
        while (row0 >= pad_off[e + 1]) ++e;
        wdp = Wd + (size_t)e * HDIM * IDIM;
    }
    const int tid = threadIdx.x, l = tid & 63, w = tid >> 6;
    const int wm = w >> 1, wn = w & 1;
    const int lr = l & 15, lg4 = l >> 4;

    int rA0, kA0, rA1, kA1, rB, kB;
    gdec(tid, rA0, kA0);
    gdec(512 + tid, rA1, kA1);
    gdec(tid, rB, kB);
    const ushort_t* srcA0 = Hm + (size_t)(row0 + rA0) * IDIM + kA0 * 8;
    const ushort_t* srcA1 = Hm + (size_t)(row0 + rA1) * IDIM + kA1 * 8;
    const ushort_t* srcB = wdp + (size_t)(col0 + rB) * IDIM + kB * 8;
    const int dA0 = tid * 8, dA1 = (512 + tid) * 8, dB = tid * 8;

    const int s_slot = (((l & 1) << 2) | lg4) ^ ((l >> 1) & 7);
    const int aoff = (wm * 32 + (lr >> 1)) * 64 + s_slot * 8;
    const int boff = (wn * 32 + (lr >> 1)) * 64 + s_slot * 8;

    f32x4 acc[4][4] = {};

#define G2_STAGE(h) do { int ko = (h) * 32; int hb_ = ((h) & 3) * 12288;       \
        gload16(srcA0 + ko, &lds[hb_ + dA0]);                                  \
        gload16(srcA1 + ko, &lds[hb_ + dA1]);                                  \
        gload16(srcB + ko, &lds[hb_ + 8192 + dB]); } while (0)

#define G2_BODY(h, VMWAIT, DOSTAGE) do {                                       \
        const int hb = ((h) & 3) * 12288;                                      \
        VMWAIT; SBAR();                                                        \
        if (DOSTAGE) G2_STAGE((h) + 3);                                        \
        s16x8 a0 = *(const s16x8*)&lds[hb + aoff];                             \
        s16x8 a1 = *(const s16x8*)&lds[hb + aoff + 512];                       \
        s16x8 a2 = *(const s16x8*)&lds[hb + aoff + 1024];                      \
        s16x8 a3 = *(const s16x8*)&lds[hb + aoff + 1536];                      \
        s16x8 b0 = *(const s16x8*)&lds[hb + 8192 + boff];                      \
        s16x8 b1 = *(const s16x8*)&lds[hb + 8192 + boff + 512];                \
        s16x8 b2 = *(const s16x8*)&lds[hb + 8192 + boff + 1024];               \
        s16x8 b3 = *(const s16x8*)&lds[hb + 8192 + boff + 1536];               \
        LGKM0();                                                               \
        __builtin_amdgcn_s_setprio(1);                                         \
        acc[0][0] = __builtin_amdgcn_mfma_f32_16x16x32_bf16(a0, b0, acc[0][0], 0, 0, 0); \
        acc[0][1] = __builtin_amdgcn_mfma_f32_16x16x32_bf16(a0, b1, acc[0][1], 0, 0, 0); \
        acc[0][2] = __builtin_amdgcn_mfma_f32_16x16x32_bf16(a0, b2, acc[0][2], 0, 0, 0); \
        acc[0][3] = __builtin_amdgcn_mfma_f32_16x16x32_bf16(a0, b3, acc[0][3], 0, 0, 0); \
        acc[1][0] = __builtin_amdgcn_mfma_f32_16x16x32_bf16(a1, b0, acc[1][0], 0, 0, 0); \
        acc[1][1] = __builtin_amdgcn_mfma_f32_16x16x32_bf16(a1, b1, acc[1][1], 0, 0, 0); \
        acc[1][2] = __builtin_amdgcn_mfma_f32_16x16x32_bf16(a1, b2, acc[1][2], 0, 0, 0); \
        acc[1][3] = __builtin_amdgcn_mfma_f32_16x16x32_bf16(a1, b3, acc[1][3], 0, 0, 0); \
        acc[2][0] = __builtin_amdgcn_mfma_f32_16x16x32_bf16(a2, b0, acc[2][0], 0, 0, 0); \
        acc[2][1] = __builtin_amdgcn_mfma_f32_16x16x32_bf16(a2, b1, acc[2][1], 0, 0, 0); \
        acc[2][2] = __builtin_amdgcn_mfma_f32_16x16x32_bf16(a2, b2, acc[2][2], 0, 0, 0); \
        acc[2][3] = __builtin_amdgcn_mfma_f32_16x16x32_bf16(a2, b3, acc[2][3], 0, 0, 0); \
        acc[3][0] = __builtin_amdgcn_mfma_f32_16x16x32_bf16(a3, b0, acc[3][0], 0, 0, 0); \
        acc[3][1] = __builtin_amdgcn_mfma_f32_16x16x32_bf16(a3, b1, acc[3][1], 0, 0, 0); \
        acc[3][2] = __builtin_amdgcn_mfma_f32_16x16x32_bf16(a3, b2, acc[3][2], 0, 0, 0); \
        acc[3][3] = __builtin_amdgcn_mfma_f32_16x16x32_bf16(a3, b3, acc[3][3], 0, 0, 0); \
        __builtin_amdgcn_s_setprio(0);                                         \
    } while (0)

    G2_STAGE(0);
    G2_STAGE(1);
    G2_STAGE(2);
    for (int h = 0; h < NH - 3; ++h) G2_BODY(h, VMW(6), 1);
    G2_BODY(NH - 3, VMW(6), 0);
    G2_BODY(NH - 2, VMW(3), 0);
    G2_BODY(NH - 1, VMW(0), 0);

#pragma unroll
    for (int mf = 0; mf < 4; ++mf) {
        int row = row0 + wm * 64 + mf * 16 + lg4 * 4;
#pragma unroll
        for (int nf = 0; nf < 4; ++nf) {
            int col = col0 + wn * 64 + nf * 16 + lr;
#pragma unroll
            for (int rr = 0; rr < 4; ++rr) {
                int rw_ = row + rr;
                if (SHARED) {
                    size_t o = (size_t)rw_ * HDIM + col;
                    out[o] = hs[o] + acc[mf][nf][rr];
                } else {
                    int tok = order[rw_];
                    if (tok >= 0) {
                        size_t o = (size_t)tok * HDIM + col;
                        out[o] += acc[mf][nf][rr];
                    }
                }
            }
        }
    }
#undef G2_STAGE
#undef G2_BODY
}

extern "C" void kernel_launch(void* const* d_in, const int* in_sizes, int n_in,
                              void* d_out, int out_size, void* d_ws, size_t ws_size,
                              hipStream_t stream) {
    const float* hs = (const float*)d_in[0];
    const float* lnw = (const float*)d_in[1];
    const float* lnb = (const float*)d_in[2];
    const float* rw = (const float*)d_in[3];
    const float* gw = (const float*)d_in[4];
    const float* uw = (const float*)d_in[5];
    const float* dw = (const float*)d_in[6];
    const float* shg = (const float*)d_in[7];
    const float* shu = (const float*)d_in[8];
    const float* shd = (const float*)d_in[9];
    float* out = (float*)d_out;

    char* p = (char*)d_ws;
    auto alloc = [&](size_t bytes) {
        void* r = (void*)p;
        p += (bytes + 255) & ~(size_t)255;
        return r;
    };
    ushort_t* xsbuf = (ushort_t*)alloc((size_t)TOTROWS * HDIM * 2);   // routed rows + normed rows
    ushort_t* hmid = (ushort_t*)alloc((size_t)TOTROWS * IDIM * 2);
    ushort_t* gwt = (ushort_t*)alloc((size_t)9 * IDIM * HDIM * 2);    // experts 0-7 + shared(8)
    ushort_t* uwt = (ushort_t*)alloc((size_t)9 * IDIM * HDIM * 2);
    ushort_t* dwt = (ushort_t*)alloc((size_t)9 * HDIM * IDIM * 2);
    int* cnt = (int*)alloc(NEXP * 4);
    int* pad_off = (int*)alloc((NEXP + 1) * 4);
    int* fill = (int*)alloc(NEXP * 4);
    int* top_idx = (int*)alloc(T_TOK * 4);
    float* top_sc = (float*)alloc(T_TOK * 4);
    int* order = (int*)alloc(RPAD_MAX * 4);

    ushort_t* normed = xsbuf + (size_t)RPAD_MAX * HDIM;

    hipMemsetAsync(cnt, 0, NEXP * 4, stream);
    hipMemsetAsync(order, 0xFF, RPAD_MAX * 4, stream);
    hipMemsetAsync(xsbuf, 0, (size_t)RPAD_MAX * HDIM * 2, stream);   // zero pad rows

    dim3 tb(32, 8);
    tcvt_gu<<<dim3(IDIM / 32, HDIM / 32, 18), tb, 0, stream>>>(gw, shg, uw, shu, gwt, uwt);
    tcvt_d<<<dim3(HDIM / 32, IDIM / 32, 9), tb, 0, stream>>>(dw, shd, dwt);

    ln_router<<<T_TOK, 256, 0, stream>>>(hs, lnw, lnb, rw, normed, top_idx, top_sc, cnt);
    scan_k<<<1, 64, 0, stream>>>(cnt, pad_off, fill);
    scatter_k<<<T_TOK, 256, 0, stream>>>(normed, top_idx, top_sc, pad_off, fill, order, xsbuf);

    // fused gemm1 over routed (rows [0,RPAD_MAX)) + shared (rows [RPAD_MAX,TOTROWS))
    {
        int RT = TOTROWS / 256, CT = IDIM / 128;
        gemm1_k<<<RT * CT, 512, 0, stream>>>(xsbuf, gwt, uwt, pad_off, hmid);
    }
    // shared expert down-proj: out = hs + shared   (must run BEFORE routed RMW)
    {
        int RT = T_TOK / 256;  // 32
        gemm2_k<1><<<RT * (HDIM / 128), 512, 0, stream>>>(
            hmid + (size_t)RPAD_MAX * IDIM, dwt, pad_off, order, hs, out, RT);
    }
    // routed down-proj: out += routed (scatter via order, plain RMW — top-1 => unique writer)
    {
        int RT = RPAD_MAX / 256;  // 40
        gemm2_k<0><<<RT * (HDIM / 128), 512, 0, stream>>>(
            hmid, dwt, pad_off, order, hs, out, RT);
    }
}

// Round 5
// 588.318 us; speedup vs baseline: 1.4305x; 1.0258x over previous
//
#include <hip/hip_runtime.h>

typedef unsigned short ushort_t;
typedef unsigned int uint_t;

#define T_TOK 8192
#define HDIM 1024
#define IDIM 2048
#define NEXP 8
#define RPAD_MAX 10240                 // 8192 + 8*256 worst-case padded routed rows
#define TOTROWS (RPAD_MAX + T_TOK)     // 18432

using f32x4 = __attribute__((ext_vector_type(4))) float;
using s16x8 = __attribute__((ext_vector_type(8))) short;

#define SBAR() do { asm volatile("" ::: "memory"); __builtin_amdgcn_s_barrier(); asm volatile("" ::: "memory"); } while (0)
#define VMW(n) asm volatile("s_waitcnt vmcnt(" #n ")" ::: "memory")
#define LGKM(n) do { asm volatile("s_waitcnt lgkmcnt(" #n ")" ::: "memory"); __builtin_amdgcn_sched_barrier(0); } while (0)

__device__ __forceinline__ float b2f(ushort_t h) {
    return __uint_as_float(((uint_t)h) << 16);
}
__device__ __forceinline__ ushort_t f2bf(float f) {
    uint_t u = __float_as_uint(f);
    uint_t r = (u + 0x7FFFu + ((u >> 16) & 1u)) >> 16;
    return (ushort_t)r;
}
__device__ __forceinline__ void gload16(const void* g, void* l) {
    __builtin_amdgcn_global_load_lds(
        (const __attribute__((address_space(1))) void*)g,
        (__attribute__((address_space(3))) void*)l, 16, 0, 0);
}
// decode staging granule: LDS granule gi (paired-row layout, XOR swizzle) -> (row, k-granule)
__device__ __forceinline__ void gdec(int gi, int& r, int& kg) {
    int prow = gi >> 3, v = (gi & 7) ^ (prow & 7);
    r = 2 * prow + (v >> 2);
    kg = v & 3;
}

// ---------------- merged transpose+convert: gate & up (R=HDIM, C=IDIM)
__global__ void tcvt_gu(const float* __restrict__ gw, const float* __restrict__ shg,
                        const float* __restrict__ uw, const float* __restrict__ shu,
                        ushort_t* __restrict__ gwt, ushort_t* __restrict__ uwt) {
    __shared__ float tile[32][33];
    int z = blockIdx.z, zz = z % 9;
    const float* src;
    ushort_t* dst;
    if (z < 9) {
        src = zz < 8 ? gw + (size_t)zz * HDIM * IDIM : shg;
        dst = gwt + (size_t)zz * IDIM * HDIM;
    } else {
        src = zz < 8 ? uw + (size_t)zz * HDIM * IDIM : shu;
        dst = uwt + (size_t)zz * IDIM * HDIM;
    }
    int c0 = blockIdx.x * 32, r0 = blockIdx.y * 32;
    int tx = threadIdx.x, ty = threadIdx.y;
#pragma unroll
    for (int i = 0; i < 32; i += 8)
        tile[ty + i][tx] = src[(size_t)(r0 + ty + i) * IDIM + c0 + tx];
    __syncthreads();
#pragma unroll
    for (int i = 0; i < 32; i += 8)
        dst[(size_t)(c0 + ty + i) * HDIM + r0 + tx] = f2bf(tile[tx][ty + i]);
}
// down (R=IDIM, C=HDIM)
__global__ void tcvt_d(const float* __restrict__ dw, const float* __restrict__ shd,
                       ushort_t* __restrict__ dwt) {
    __shared__ float tile[32][33];
    int z = blockIdx.z;
    const float* src = z < 8 ? dw + (size_t)z * IDIM * HDIM : shd;
    ushort_t* dst = dwt + (size_t)z * HDIM * IDIM;
    int c0 = blockIdx.x * 32, r0 = blockIdx.y * 32;
    int tx = threadIdx.x, ty = threadIdx.y;
#pragma unroll
    for (int i = 0; i < 32; i += 8)
        tile[ty + i][tx] = src[(size_t)(r0 + ty + i) * HDIM + c0 + tx];
    __syncthreads();
#pragma unroll
    for (int i = 0; i < 32; i += 8)
        dst[(size_t)(c0 + ty + i) * IDIM + r0 + tx] = f2bf(tile[tx][ty + i]);
}

// ---------------- layernorm + router
__global__ void ln_router(const float* __restrict__ x, const float* __restrict__ lnw,
                          const float* __restrict__ lnb, const float* __restrict__ rw,
                          ushort_t* __restrict__ normed, int* __restrict__ top_idx,
                          float* __restrict__ top_score, int* __restrict__ cnt) {
    int t = blockIdx.x, tid = threadIdx.x;
    const float* xr = x + (size_t)t * HDIM;
    float v[4];
    float s = 0.f, ss = 0.f;
#pragma unroll
    for (int i = 0; i < 4; i++) {
        v[i] = xr[tid + i * 256];
        s += v[i];
        ss += v[i] * v[i];
    }
#pragma unroll
    for (int o = 32; o; o >>= 1) {
        s += __shfl_down(s, o);
        ss += __shfl_down(ss, o);
    }
    __shared__ float rs_[4], rss_[4], stats[2];
    int wid = tid >> 6, lane = tid & 63;
    if (!lane) { rs_[wid] = s; rss_[wid] = ss; }
    __syncthreads();
    if (!tid) {
        float S = rs_[0] + rs_[1] + rs_[2] + rs_[3];
        float SS = rss_[0] + rss_[1] + rss_[2] + rss_[3];
        float mu = S * (1.f / HDIM);
        float var = SS * (1.f / HDIM) - mu * mu;
        stats[0] = mu;
        stats[1] = rsqrtf(var + 1e-5f);
    }
    __syncthreads();
    float mu = stats[0], rsg = stats[1];
    float lg[8] = {0, 0, 0, 0, 0, 0, 0, 0};
#pragma unroll
    for (int i = 0; i < 4; i++) {
        int h = tid + i * 256;
        float xn = (v[i] - mu) * rsg * lnw[h] + lnb[h];
        normed[(size_t)t * HDIM + h] = f2bf(xn);
        const float* rwh = rw + (size_t)h * NEXP;
#pragma unroll
        for (int e = 0; e < 8; e++) lg[e] += xn * rwh[e];
    }
#pragma unroll
    for (int o = 32; o; o >>= 1)
#pragma unroll
        for (int e = 0; e < 8; e++) lg[e] += __shfl_down(lg[e], o);
    __shared__ float lred[4][8];
    if (!lane)
#pragma unroll
        for (int e = 0; e < 8; e++) lred[wid][e] = lg[e];
    __syncthreads();
    if (!tid) {
        float best = -1e30f;
        int bi = 0;
#pragma unroll
        for (int e = 0; e < 8; e++) {
            float L = lred[0][e] + lred[1][e] + lred[2][e] + lred[3][e];
            if (L > best) { best = L; bi = e; }
        }
        top_idx[t] = bi;
        top_score[t] = 1.f / (1.f + __expf(-best));
        atomicAdd(&cnt[bi], 1);
    }
}

__global__ void scan_k(const int* __restrict__ cnt, int* __restrict__ pad_off,
                       int* __restrict__ fill) {
    if (threadIdx.x == 0) {
        int o = 0;
        for (int e = 0; e < NEXP; e++) {
            pad_off[e] = o;
            o += (cnt[e] + 255) & ~255;
        }
        pad_off[NEXP] = o;
    }
    if (threadIdx.x < NEXP) fill[threadIdx.x] = 0;
}

__global__ void scatter_k(const ushort_t* __restrict__ normed, const int* __restrict__ top_idx,
                          const float* __restrict__ top_score, const int* __restrict__ pad_off,
                          int* __restrict__ fill, int* __restrict__ order,
                          ushort_t* __restrict__ xs) {
    int t = blockIdx.x, tid = threadIdx.x;
    __shared__ int spos;
    if (!tid) {
        int e = top_idx[t];
        int p = pad_off[e] + atomicAdd(&fill[e], 1);
        order[p] = t;
        spos = p;
    }
    __syncthreads();
    int pos = spos;
    float sc = top_score[t];
    const ushort4* src = (const ushort4*)(normed + (size_t)t * HDIM);
    ushort4* dst = (ushort4*)(xs + (size_t)pos * HDIM);
    ushort4 a = src[tid];
    a.x = f2bf(b2f(a.x) * sc);
    a.y = f2bf(b2f(a.y) * sc);
    a.z = f2bf(b2f(a.z) * sc);
    a.w = f2bf(b2f(a.w) * sc);
    dst[tid] = a;
}

// ================= GEMM1 (fused routed+shared): hmid = silu(X@Wg^T)*(X@Wu^T)
// BM=256, BN=128(g)+128(u), K-half ring of 4 x 32KB LDS buffers. 8 waves 2Mx4N.
// rt-major block order: concurrent blocks share the A-panel (L2-resident).
__global__ __launch_bounds__(512, 2) void gemm1_k(
    const ushort_t* __restrict__ X, const ushort_t* __restrict__ Wg,
    const ushort_t* __restrict__ Wu, const int* __restrict__ pad_off,
    ushort_t* __restrict__ hmid) {
    __shared__ __align__(16) ushort_t lds[4 * 16384];  // 128 KiB
    const int RT = TOTROWS / 256, CT = IDIM / 128;  // 72, 16
    const int NH = HDIM / 32;                        // 32 halves
    int nwg = RT * CT;
    int bid = blockIdx.x;
    int q = nwg >> 3, r = nwg & 7;
    int xcd = bid & 7, idx = bid >> 3;
    int wg = (xcd < r ? xcd * (q + 1) : r * (q + 1) + (xcd - r) * q) + idx;
    int rt = wg / CT, ct = wg % CT;              // rt-major
    int row0 = rt * 256, col0 = ct * 128;
    int e;
    if (row0 >= RPAD_MAX) e = 8;
    else {
        if (row0 >= pad_off[NEXP]) return;
        e = 0;
        while (row0 >= pad_off[e + 1]) ++e;
    }
    const ushort_t* wgp = Wg + (size_t)e * IDIM * HDIM;
    const ushort_t* wup = Wu + (size_t)e * IDIM * HDIM;

    const int tid = threadIdx.x, l = tid & 63, w = tid >> 6;
    const int wm = w >> 2, wn = w & 3;
    const int lr = l & 15, lg4 = l >> 4;

    // staging: 16B-per-lane stride ONLY (global_load_lds writes wave-base + lane*16B)
    int rA0, kA0, rA1, kA1, rB, kB;
    gdec(tid, rA0, kA0);          // granules [0,512)    -> rows 0..127
    gdec(512 + tid, rA1, kA1);    // granules [512,1024) -> rows 128..255
    gdec(tid, rB, kB);
    const ushort_t* srcA0 = X + (size_t)(row0 + rA0) * HDIM + kA0 * 8;
    const ushort_t* srcA1 = X + (size_t)(row0 + rA1) * HDIM + kA1 * 8;
    const ushort_t* srcBg = wgp + (size_t)(col0 + rB) * HDIM + kB * 8;
    const ushort_t* srcBu = wup + (size_t)(col0 + rB) * HDIM + kB * 8;
    const int dA0 = tid * 8, dA1 = (512 + tid) * 8, dB = tid * 8;

    // fragment read constants
    const int s_slot = (((l & 1) << 2) | lg4) ^ ((l >> 1) & 7);
    const int aoff = (wm * 64 + (lr >> 1)) * 64 + s_slot * 8;
    const int boff = (wn * 16 + (lr >> 1)) * 64 + s_slot * 8;

    f32x4 accg[8][2] = {};
    f32x4 accu[8][2] = {};

#define G1_STAGE(h) do { int ko = (h) * 32; int hb_ = ((h) & 3) * 16384;       \
        gload16(srcA0 + ko, &lds[hb_ + dA0]);                                  \
        gload16(srcA1 + ko, &lds[hb_ + dA1]);                                  \
        gload16(srcBg + ko, &lds[hb_ + 8192 + dB]);                            \
        gload16(srcBu + ko, &lds[hb_ + 12288 + dB]); } while (0)

    // m201-style phase: ds_read BEFORE barrier (latency hides under barrier
    // convergence + other waves' MFMA), counted vmcnt, split lgkm waits.
#define G1_PH(h, VMWAIT, DOSTAGE) do {                                         \
        const int hb = ((h) & 3) * 16384;                                      \
        s16x8 av[8], bv[4];                                                    \
        _Pragma("unroll")                                                      \
        for (int i = 0; i < 4; ++i) av[i] = *(const s16x8*)&lds[hb + aoff + i * 512]; \
        _Pragma("unroll")                                                      \
        for (int i = 0; i < 2; ++i) bv[i] = *(const s16x8*)&lds[hb + 8192 + boff + i * 512]; \
        _Pragma("unroll")                                                      \
        for (int i = 0; i < 2; ++i) bv[2 + i] = *(const s16x8*)&lds[hb + 12288 + boff + i * 512]; \
        _Pragma("unroll")                                                      \
        for (int i = 0; i < 4; ++i) av[4 + i] = *(const s16x8*)&lds[hb + aoff + 2048 + i * 512]; \
        if (DOSTAGE) G1_STAGE((h) + 3);                                        \
        VMWAIT;                                                                \
        SBAR();                                                                \
        LGKM(4);                                                               \
        __builtin_amdgcn_s_setprio(1);                                         \
        _Pragma("unroll")                                                      \
        for (int m = 0; m < 4; ++m) {                                          \
            accg[m][0] = __builtin_amdgcn_mfma_f32_16x16x32_bf16(av[m], bv[0], accg[m][0], 0, 0, 0); \
            accg[m][1] = __builtin_amdgcn_mfma_f32_16x16x32_bf16(av[m], bv[1], accg[m][1], 0, 0, 0); \
            accu[m][0] = __builtin_amdgcn_mfma_f32_16x16x32_bf16(av[m], bv[2], accu[m][0], 0, 0, 0); \
            accu[m][1] = __builtin_amdgcn_mfma_f32_16x16x32_bf16(av[m], bv[3], accu[m][1], 0, 0, 0); \
        }                                                                      \
        __builtin_amdgcn_s_setprio(0);                                         \
        LGKM(0);                                                               \
        __builtin_amdgcn_s_setprio(1);                                         \
        _Pragma("unroll")                                                      \
        for (int m = 0; m < 4; ++m) {                                          \
            accg[4 + m][0] = __builtin_amdgcn_mfma_f32_16x16x32_bf16(av[4 + m], bv[0], accg[4 + m][0], 0, 0, 0); \
            accg[4 + m][1] = __builtin_amdgcn_mfma_f32_16x16x32_bf16(av[4 + m], bv[1], accg[4 + m][1], 0, 0, 0); \
            accu[4 + m][0] = __builtin_amdgcn_mfma_f32_16x16x32_bf16(av[4 + m], bv[2], accu[4 + m][0], 0, 0, 0); \
            accu[4 + m][1] = __builtin_amdgcn_mfma_f32_16x16x32_bf16(av[4 + m], bv[3], accu[4 + m][1], 0, 0, 0); \
        }                                                                      \
        __builtin_amdgcn_s_setprio(0);                                         \
        SBAR();                                                                \
    } while (0)

    G1_STAGE(0);
    G1_STAGE(1);
    G1_STAGE(2);
    VMW(8);
    SBAR();
    for (int h = 0; h < NH - 3; ++h) G1_PH(h, VMW(8), 1);
    G1_PH(NH - 3, VMW(4), 0);
    G1_PH(NH - 2, VMW(0), 0);
    G1_PH(NH - 1, VMW(0), 0);

#pragma unroll
    for (int mf = 0; mf < 8; ++mf) {
        int row = row0 + wm * 128 + mf * 16 + lg4 * 4;
#pragma unroll
        for (int nf = 0; nf < 2; ++nf) {
            int col = col0 + wn * 32 + nf * 16 + lr;
#pragma unroll
            for (int rr = 0; rr < 4; ++rr) {
                float g = accg[mf][nf][rr], u = accu[mf][nf][rr];
                float val = g / (1.f + __expf(-g)) * u;
                hmid[(size_t)(row + rr) * IDIM + col] = f2bf(val);
            }
        }
    }
#undef G1_STAGE
#undef G1_PH
}

// ================= GEMM2: out = Hm @ Wd^T (+ hs). BM=256, BN=128, 4x24KB ring.
// SHARED=0 (routed, runs FIRST): out[tok] = acc (plain store; top-1 => each token once)
// SHARED=1 (shared, runs SECOND): out[tok] += hs[tok] + acc
template <int SHARED>
__global__ __launch_bounds__(512, 2) void gemm2_k(
    const ushort_t* __restrict__ Hm, const ushort_t* __restrict__ Wd,
    const int* __restrict__ pad_off, const int* __restrict__ order,
    const float* __restrict__ hs, float* __restrict__ out, int RT) {
    __shared__ __align__(16) ushort_t lds[4 * 12288];  // 96 KiB
    const int CT = HDIM / 128;           // 8
    const int NH = IDIM / 32;            // 64 halves
    int nwg = RT * CT;
    int bid = blockIdx.x;
    int q = nwg >> 3, r = nwg & 7;
    int xcd = bid & 7, idx = bid >> 3;
    int wg = (xcd < r ? xcd * (q + 1) : r * (q + 1) + (xcd - r) * q) + idx;
    int rt = wg / CT, ct = wg % CT;      // rt-major
    int row0 = rt * 256, col0 = ct * 128;
    const ushort_t* wdp;
    if (SHARED) {
        wdp = Wd + (size_t)8 * HDIM * IDIM;
    } else {
        if (row0 >= pad_off[NEXP]) return;
        int e = 0;
        while (row0 >= pad_off[e + 1]) ++e;
        wdp = Wd + (size_t)e * HDIM * IDIM;
    }
    const int tid = threadIdx.x, l = tid & 63, w = tid >> 6;
    const int wm = w >> 1, wn = w & 1;
    const int lr = l & 15, lg4 = l >> 4;

    int rA0, kA0, rA1, kA1, rB, kB;
    gdec(tid, rA0, kA0);
    gdec(512 + tid, rA1, kA1);
    gdec(tid, rB, kB);
    const ushort_t* srcA0 = Hm + (size_t)(row0 + rA0) * IDIM + kA0 * 8;
    const ushort_t* srcA1 = Hm + (size_t)(row0 + rA1) * IDIM + kA1 * 8;
    const ushort_t* srcB = wdp + (size_t)(col0 + rB) * IDIM + kB * 8;
    const int dA0 = tid * 8, dA1 = (512 + tid) * 8, dB = tid * 8;

    const int s_slot = (((l & 1) << 2) | lg4) ^ ((l >> 1) & 7);
    const int aoff = (wm * 32 + (lr >> 1)) * 64 + s_slot * 8;
    const int boff = (wn * 32 + (lr >> 1)) * 64 + s_slot * 8;

    f32x4 acc[4][4] = {};

#define G2_STAGE(h) do { int ko = (h) * 32; int hb_ = ((h) & 3) * 12288;       \
        gload16(srcA0 + ko, &lds[hb_ + dA0]);                                  \
        gload16(srcA1 + ko, &lds[hb_ + dA1]);                                  \
        gload16(srcB + ko, &lds[hb_ + 8192 + dB]); } while (0)

#define G2_PH(h, VMWAIT, DOSTAGE) do {                                         \
        const int hb = ((h) & 3) * 12288;                                      \
        s16x8 av[4], bv[4];                                                    \
        _Pragma("unroll")                                                      \
        for (int i = 0; i < 4; ++i) av[i] = *(const s16x8*)&lds[hb + aoff + i * 512]; \
        _Pragma("unroll")                                                      \
        for (int i = 0; i < 4; ++i) bv[i] = *(const s16x8*)&lds[hb + 8192 + boff + i * 512]; \
        if (DOSTAGE) G2_STAGE((h) + 3);                                        \
        VMWAIT;                                                                \
        SBAR();                                                                \
        LGKM(0);                                                               \
        __builtin_amdgcn_s_setprio(1);                                         \
        _Pragma("unroll")                                                      \
        for (int m = 0; m < 4; ++m)                                            \
            _Pragma("unroll")                                                  \
            for (int n = 0; n < 4; ++n)                                        \
                acc[m][n] = __builtin_amdgcn_mfma_f32_16x16x32_bf16(av[m], bv[n], acc[m][n], 0, 0, 0); \
        __builtin_amdgcn_s_setprio(0);                                         \
        SBAR();                                                                \
    } while (0)

    G2_STAGE(0);
    G2_STAGE(1);
    G2_STAGE(2);
    VMW(6);
    SBAR();
    for (int h = 0; h < NH - 3; ++h) G2_PH(h, VMW(6), 1);
    G2_PH(NH - 3, VMW(3), 0);
    G2_PH(NH - 2, VMW(0), 0);
    G2_PH(NH - 1, VMW(0), 0);

#pragma unroll
    for (int mf = 0; mf < 4; ++mf) {
        int row = row0 + wm * 64 + mf * 16 + lg4 * 4;
#pragma unroll
        for (int nf = 0; nf < 4; ++nf) {
            int col = col0 + wn * 64 + nf * 16 + lr;
#pragma unroll
            for (int rr = 0; rr < 4; ++rr) {
                int rw_ = row + rr;
                if (SHARED) {
                    size_t o = (size_t)rw_ * HDIM + col;
                    out[o] += hs[o] + acc[mf][nf][rr];
                } else {
                    int tok = order[rw_];
                    if (tok >= 0) {
                        size_t o = (size_t)tok * HDIM + col;
                        out[o] = acc[mf][nf][rr];
                    }
                }
            }
        }
    }
#undef G2_STAGE
#undef G2_PH
}

extern "C" void kernel_launch(void* const* d_in, const int* in_sizes, int n_in,
                              void* d_out, int out_size, void* d_ws, size_t ws_size,
                              hipStream_t stream) {
    const float* hs = (const float*)d_in[0];
    const float* lnw = (const float*)d_in[1];
    const float* lnb = (const float*)d_in[2];
    const float* rw = (const float*)d_in[3];
    const float* gw = (const float*)d_in[4];
    const float* uw = (const float*)d_in[5];
    const float* dw = (const float*)d_in[6];
    const float* shg = (const float*)d_in[7];
    const float* shu = (const float*)d_in[8];
    const float* shd = (const float*)d_in[9];
    float* out = (float*)d_out;

    char* p = (char*)d_ws;
    auto alloc = [&](size_t bytes) {
        void* r = (void*)p;
        p += (bytes + 255) & ~(size_t)255;
        return r;
    };
    ushort_t* xsbuf = (ushort_t*)alloc((size_t)TOTROWS * HDIM * 2);   // routed rows + normed rows
    ushort_t* hmid = (ushort_t*)alloc((size_t)TOTROWS * IDIM * 2);
    ushort_t* gwt = (ushort_t*)alloc((size_t)9 * IDIM * HDIM * 2);    // experts 0-7 + shared(8)
    ushort_t* uwt = (ushort_t*)alloc((size_t)9 * IDIM * HDIM * 2);
    ushort_t* dwt = (ushort_t*)alloc((size_t)9 * HDIM * IDIM * 2);
    int* cnt = (int*)alloc(NEXP * 4);
    int* pad_off = (int*)alloc((NEXP + 1) * 4);
    int* fill = (int*)alloc(NEXP * 4);
    int* top_idx = (int*)alloc(T_TOK * 4);
    float* top_sc = (float*)alloc(T_TOK * 4);
    int* order = (int*)alloc(RPAD_MAX * 4);

    ushort_t* normed = xsbuf + (size_t)RPAD_MAX * HDIM;

    hipMemsetAsync(cnt, 0, NEXP * 4, stream);
    hipMemsetAsync(order, 0xFF, RPAD_MAX * 4, stream);
    hipMemsetAsync(xsbuf, 0, (size_t)RPAD_MAX * HDIM * 2, stream);   // zero pad rows

    dim3 tb(32, 8);
    tcvt_gu<<<dim3(IDIM / 32, HDIM / 32, 18), tb, 0, stream>>>(gw, shg, uw, shu, gwt, uwt);
    tcvt_d<<<dim3(HDIM / 32, IDIM / 32, 9), tb, 0, stream>>>(dw, shd, dwt);

    ln_router<<<T_TOK, 256, 0, stream>>>(hs, lnw, lnb, rw, normed, top_idx, top_sc, cnt);
    scan_k<<<1, 64, 0, stream>>>(cnt, pad_off, fill);
    scatter_k<<<T_TOK, 256, 0, stream>>>(normed, top_idx, top_sc, pad_off, fill, order, xsbuf);

    // fused gemm1 over routed (rows [0,RPAD_MAX)) + shared (rows [RPAD_MAX,TOTROWS))
    {
        int RT = TOTROWS / 256, CT = IDIM / 128;
        gemm1_k<<<RT * CT, 512, 0, stream>>>(xsbuf, gwt, uwt, pad_off, hmid);
    }
    // routed down-proj FIRST: out[tok] = acc (plain store — every token exactly once)
    {
        int RT = RPAD_MAX / 256;  // 40
        gemm2_k<0><<<RT * (HDIM / 128), 512, 0, stream>>>(
            hmid, dwt, pad_off, order, hs, out, RT);
    }
    // shared down-proj SECOND: out += hs + acc
    {
        int RT = T_TOK / 256;  // 32
        gemm2_k<1><<<RT * (HDIM / 128), 512, 0, stream>>>(
            hmid + (size_t)RPAD_MAX * IDIM, dwt, pad_off, order, hs, out, RT);
    }
}

// Round 7
// 577.581 us; speedup vs baseline: 1.4571x; 1.0186x over previous
//
#include <hip/hip_runtime.h>

typedef unsigned short ushort_t;
typedef unsigned int uint_t;

#define T_TOK 8192
#define HDIM 1024
#define IDIM 2048
#define NEXP 8
#define RPAD_MAX 10240                 // 8192 + 8*256 worst-case padded routed rows
#define TOTROWS (RPAD_MAX + T_TOK)     // 18432

using f32x4 = __attribute__((ext_vector_type(4))) float;
using s16x8 = __attribute__((ext_vector_type(8))) short;

#define SBAR() do { asm volatile("" ::: "memory"); __builtin_amdgcn_s_barrier(); asm volatile("" ::: "memory"); } while (0)
#define VMW(n) asm volatile("s_waitcnt vmcnt(" #n ")" ::: "memory")
#define LGKM(n) do { asm volatile("s_waitcnt lgkmcnt(" #n ")" ::: "memory"); __builtin_amdgcn_sched_barrier(0); } while (0)

__device__ __forceinline__ float b2f(ushort_t h) {
    return __uint_as_float(((uint_t)h) << 16);
}
__device__ __forceinline__ ushort_t f2bf(float f) {
    uint_t u = __float_as_uint(f);
    uint_t r = (u + 0x7FFFu + ((u >> 16) & 1u)) >> 16;
    return (ushort_t)r;
}
__device__ __forceinline__ void gload16(const void* g, void* l) {
    __builtin_amdgcn_global_load_lds(
        (const __attribute__((address_space(1))) void*)g,
        (__attribute__((address_space(3))) void*)l, 16, 0, 0);
}
// decode staging granule: LDS granule gi (paired-row layout, XOR swizzle) -> (row, k-granule)
__device__ __forceinline__ void gdec(int gi, int& r, int& kg) {
    int prow = gi >> 3, v = (gi & 7) ^ (prow & 7);
    r = 2 * prow + (v >> 2);
    kg = v & 3;
}
// 2-D super-block scheduler: each XCD's 32 co-resident blocks form a 4rt x 8ct
// rectangle -> distinct staged panels per XCD per phase = 4 A + 8 W (192 KB)
// instead of 32 (512 KB). bid->XCD model: round-robin on bid&7.
__device__ __forceinline__ void sbmap(int bid, int SBC, int NSB, int& rt, int& ct) {
    int x = bid & 7, j = bid >> 3;
    int r = j >> 5, pos = j & 31;
    int sb = r * 8 + x;
    int rem = NSB - r * 8;
    if (rem < 8) {                       // tail round: XCD groups share a super-block
        int share = 8 / rem;
        int cap = 32 / share;
        sb = r * 8 + x / share;
        pos = (x % share) * cap + (pos % cap);
    }
    int sbr = sb / SBC, sbc = sb % SBC;
    rt = sbr * 4 + (pos >> 3);
    ct = sbc * 8 + (pos & 7);
}

// ---------------- transpose + fp32->bf16, 64x64 tiles, ushort4 writes
// z-table: gate(0-8: gw experts + shg), up(9-17), down(18-26: dw + shd)
// Grid is (32,16,27); for down matrices (z>=18) the block-index roles are
// swapped in-kernel (their src is [IDIM][HDIM] = transposed extents).
__global__ void tcvt64(const float* __restrict__ gw, const float* __restrict__ shg,
                       const float* __restrict__ uw, const float* __restrict__ shu,
                       const float* __restrict__ dw, const float* __restrict__ shd,
                       ushort_t* __restrict__ gwt, ushort_t* __restrict__ uwt,
                       ushort_t* __restrict__ dwt) {
    __shared__ float tile[64][65];
    int z = blockIdx.z;
    const float* src;
    ushort_t* dst;
    int R, C, bx = blockIdx.x, by = blockIdx.y;
    if (z < 18) {                       // gate/up: src [H][I], dst [I][H]
        int zz = z % 9;
        R = HDIM; C = IDIM;
        if (z < 9) { src = zz < 8 ? gw + (size_t)zz * HDIM * IDIM : shg; dst = gwt + (size_t)zz * IDIM * HDIM; }
        else       { src = zz < 8 ? uw + (size_t)zz * HDIM * IDIM : shu; dst = uwt + (size_t)zz * IDIM * HDIM; }
    } else {                            // down: src [I][H], dst [H][I]
        int zz = z - 18;
        R = IDIM; C = HDIM;
        src = zz < 8 ? dw + (size_t)zz * IDIM * HDIM : shd;
        dst = dwt + (size_t)zz * HDIM * IDIM;
        int t = bx; bx = by; by = t;    // swap: 16 col-tiles x 32 row-tiles
    }
    int c0 = bx * 64, r0 = by * 64;
    int tx = threadIdx.x, ty = threadIdx.y;       // (64,4)
#pragma unroll
    for (int i = 0; i < 16; ++i)
        tile[ty + i * 4][tx] = src[(size_t)(r0 + ty + i * 4) * C + c0 + tx];
    __syncthreads();
    int tid = ty * 64 + tx;
    int rr = (tid & 15) * 4, cc0 = tid >> 4;      // rr 0..60, cc0 0..15
#pragma unroll
    for (int it = 0; it < 4; ++it) {
        int c = cc0 + it * 16;
        ushort4 v;
        v.x = f2bf(tile[rr + 0][c]);
        v.y = f2bf(tile[rr + 1][c]);
        v.z = f2bf(tile[rr + 2][c]);
        v.w = f2bf(tile[rr + 3][c]);
        *(ushort4*)&dst[(size_t)(c0 + c) * R + r0 + rr] = v;
    }
}

// ---------------- layernorm + router
__global__ void ln_router(const float* __restrict__ x, const float* __restrict__ lnw,
                          const float* __restrict__ lnb, const float* __restrict__ rw,
                          ushort_t* __restrict__ normed, int* __restrict__ top_idx,
                          float* __restrict__ top_score, int* __restrict__ cnt) {
    int t = blockIdx.x, tid = threadIdx.x;
    const float* xr = x + (size_t)t * HDIM;
    float v[4];
    float s = 0.f, ss = 0.f;
#pragma unroll
    for (int i = 0; i < 4; i++) {
        v[i] = xr[tid + i * 256];
        s += v[i];
        ss += v[i] * v[i];
    }
#pragma unroll
    for (int o = 32; o; o >>= 1) {
        s += __shfl_down(s, o);
        ss += __shfl_down(ss, o);
    }
    __shared__ float rs_[4], rss_[4], stats[2];
    int wid = tid >> 6, lane = tid & 63;
    if (!lane) { rs_[wid] = s; rss_[wid] = ss; }
    __syncthreads();
    if (!tid) {
        float S = rs_[0] + rs_[1] + rs_[2] + rs_[3];
        float SS = rss_[0] + rss_[1] + rss_[2] + rss_[3];
        float mu = S * (1.f / HDIM);
        float var = SS * (1.f / HDIM) - mu * mu;
        stats[0] = mu;
        stats[1] = rsqrtf(var + 1e-5f);
    }
    __syncthreads();
    float mu = stats[0], rsg = stats[1];
    float lg[8] = {0, 0, 0, 0, 0, 0, 0, 0};
#pragma unroll
    for (int i = 0; i < 4; i++) {
        int h = tid + i * 256;
        float xn = (v[i] - mu) * rsg * lnw[h] + lnb[h];
        normed[(size_t)t * HDIM + h] = f2bf(xn);
        const float* rwh = rw + (size_t)h * NEXP;
#pragma unroll
        for (int e = 0; e < 8; e++) lg[e] += xn * rwh[e];
    }
#pragma unroll
    for (int o = 32; o; o >>= 1)
#pragma unroll
        for (int e = 0; e < 8; e++) lg[e] += __shfl_down(lg[e], o);
    __shared__ float lred[4][8];
    if (!lane)
#pragma unroll
        for (int e = 0; e < 8; e++) lred[wid][e] = lg[e];
    __syncthreads();
    if (!tid) {
        float best = -1e30f;
        int bi = 0;
#pragma unroll
        for (int e = 0; e < 8; e++) {
            float L = lred[0][e] + lred[1][e] + lred[2][e] + lred[3][e];
            if (L > best) { best = L; bi = e; }
        }
        top_idx[t] = bi;
        top_score[t] = 1.f / (1.f + __expf(-best));
        atomicAdd(&cnt[bi], 1);
    }
}

__global__ void scan_k(const int* __restrict__ cnt, int* __restrict__ pad_off,
                       int* __restrict__ fill) {
    if (threadIdx.x == 0) {
        int o = 0;
        for (int e = 0; e < NEXP; e++) {
            pad_off[e] = o;
            o += (cnt[e] + 255) & ~255;
        }
        pad_off[NEXP] = o;
    }
    if (threadIdx.x < NEXP) fill[threadIdx.x] = 0;
}

__global__ void scatter_k(const ushort_t* __restrict__ normed, const int* __restrict__ top_idx,
                          const float* __restrict__ top_score, const int* __restrict__ pad_off,
                          int* __restrict__ fill, int* __restrict__ order,
                          ushort_t* __restrict__ xs) {
    int t = blockIdx.x, tid = threadIdx.x;
    __shared__ int spos;
    if (!tid) {
        int e = top_idx[t];
        int p = pad_off[e] + atomicAdd(&fill[e], 1);
        order[p] = t;
        spos = p;
    }
    __syncthreads();
    int pos = spos;
    float sc = top_score[t];
    const ushort4* src = (const ushort4*)(normed + (size_t)t * HDIM);
    ushort4* dst = (ushort4*)(xs + (size_t)pos * HDIM);
    ushort4 a = src[tid];
    a.x = f2bf(b2f(a.x) * sc);
    a.y = f2bf(b2f(a.y) * sc);
    a.z = f2bf(b2f(a.z) * sc);
    a.w = f2bf(b2f(a.w) * sc);
    dst[tid] = a;
}

// ================= GEMM1 (fused routed+shared): hmid = silu(X@Wg^T)*(X@Wu^T)
// BM=256, BN=128(g)+128(u), K-half ring of 4 x 32KB LDS buffers. 8 waves 2Mx4N.
__global__ __launch_bounds__(512, 2) void gemm1_k(
    const ushort_t* __restrict__ X, const ushort_t* __restrict__ Wg,
    const ushort_t* __restrict__ Wu, const int* __restrict__ pad_off,
    ushort_t* __restrict__ hmid) {
    __shared__ __align__(16) ushort_t lds[4 * 16384];  // 128 KiB
    const int CT = IDIM / 128;                       // 16
    const int NH = HDIM / 32;                        // 32 halves
    int rt, ct;
    sbmap(blockIdx.x, CT / 8, (TOTROWS / 256 / 4) * (CT / 8), rt, ct);
    int row0 = rt * 256, col0 = ct * 128;
    int e;
    if (row0 >= RPAD_MAX) e = 8;
    else {
        if (row0 >= pad_off[NEXP]) return;
        e = 0;
        while (e < 7 && row0 >= pad_off[e + 1]) ++e;
    }
    const ushort_t* wgp = Wg + (size_t)e * IDIM * HDIM;
    const ushort_t* wup = Wu + (size_t)e * IDIM * HDIM;

    const int tid = threadIdx.x, l = tid & 63, w = tid >> 6;
    const int wm = w >> 2, wn = w & 3;
    const int lr = l & 15, lg4 = l >> 4;

    // staging: 16B-per-lane stride ONLY (global_load_lds writes wave-base + lane*16B)
    int rA0, kA0, rA1, kA1, rB, kB;
    gdec(tid, rA0, kA0);          // granules [0,512)    -> rows 0..127
    gdec(512 + tid, rA1, kA1);    // granules [512,1024) -> rows 128..255
    gdec(tid, rB, kB);
    const ushort_t* srcA0 = X + (size_t)(row0 + rA0) * HDIM + kA0 * 8;
    const ushort_t* srcA1 = X + (size_t)(row0 + rA1) * HDIM + kA1 * 8;
    const ushort_t* srcBg = wgp + (size_t)(col0 + rB) * HDIM + kB * 8;
    const ushort_t* srcBu = wup + (size_t)(col0 + rB) * HDIM + kB * 8;
    const int dA0 = tid * 8, dA1 = (512 + tid) * 8, dB = tid * 8;

    // fragment read constants
    const int s_slot = (((l & 1) << 2) | lg4) ^ ((l >> 1) & 7);
    const int aoff = (wm * 64 + (lr >> 1)) * 64 + s_slot * 8;
    const int boff = (wn * 16 + (lr >> 1)) * 64 + s_slot * 8;

    f32x4 accg[8][2] = {};
    f32x4 accu[8][2] = {};

#define G1_STAGE(h) do { int ko = (h) * 32; int hb_ = ((h) & 3) * 16384;       \
        gload16(srcA0 + ko, &lds[hb_ + dA0]);                                  \
        gload16(srcA1 + ko, &lds[hb_ + dA1]);                                  \
        gload16(srcBg + ko, &lds[hb_ + 8192 + dB]);                            \
        gload16(srcBu + ko, &lds[hb_ + 12288 + dB]); } while (0)

#define G1_PH(h, VMWAIT, DOSTAGE) do {                                         \
        const int hb = ((h) & 3) * 16384;                                      \
        s16x8 av[8], bv[4];                                                    \
        _Pragma("unroll")                                                      \
        for (int i = 0; i < 4; ++i) av[i] = *(const s16x8*)&lds[hb + aoff + i * 512]; \
        _Pragma("unroll")                                                      \
        for (int i = 0; i < 2; ++i) bv[i] = *(const s16x8*)&lds[hb + 8192 + boff + i * 512]; \
        _Pragma("unroll")                                                      \
        for (int i = 0; i < 2; ++i) bv[2 + i] = *(const s16x8*)&lds[hb + 12288 + boff + i * 512]; \
        _Pragma("unroll")                                                      \
        for (int i = 0; i < 4; ++i) av[4 + i] = *(const s16x8*)&lds[hb + aoff + 2048 + i * 512]; \
        if (DOSTAGE) G1_STAGE((h) + 3);                                        \
        VMWAIT;                                                                \
        SBAR();                                                                \
        LGKM(4);                                                               \
        __builtin_amdgcn_s_setprio(1);                                         \
        _Pragma("unroll")                                                      \
        for (int m = 0; m < 4; ++m) {                                          \
            accg[m][0] = __builtin_amdgcn_mfma_f32_16x16x32_bf16(av[m], bv[0], accg[m][0], 0, 0, 0); \
            accg[m][1] = __builtin_amdgcn_mfma_f32_16x16x32_bf16(av[m], bv[1], accg[m][1], 0, 0, 0); \
            accu[m][0] = __builtin_amdgcn_mfma_f32_16x16x32_bf16(av[m], bv[2], accu[m][0], 0, 0, 0); \
            accu[m][1] = __builtin_amdgcn_mfma_f32_16x16x32_bf16(av[m], bv[3], accu[m][1], 0, 0, 0); \
        }                                                                      \
        __builtin_amdgcn_s_setprio(0);                                         \
        LGKM(0);                                                               \
        __builtin_amdgcn_s_setprio(1);                                         \
        _Pragma("unroll")                                                      \
        for (int m = 0; m < 4; ++m) {                                          \
            accg[4 + m][0] = __builtin_amdgcn_mfma_f32_16x16x32_bf16(av[4 + m], bv[0], accg[4 + m][0], 0, 0, 0); \
            accg[4 + m][1] = __builtin_amdgcn_mfma_f32_16x16x32_bf16(av[4 + m], bv[1], accg[4 + m][1], 0, 0, 0); \
            accu[4 + m][0] = __builtin_amdgcn_mfma_f32_16x16x32_bf16(av[4 + m], bv[2], accu[4 + m][0], 0, 0, 0); \
            accu[4 + m][1] = __builtin_amdgcn_mfma_f32_16x16x32_bf16(av[4 + m], bv[3], accu[4 + m][1], 0, 0, 0); \
        }                                                                      \
        __builtin_amdgcn_s_setprio(0);                                         \
        SBAR();                                                                \
    } while (0)

    G1_STAGE(0);
    G1_STAGE(1);
    G1_STAGE(2);
    VMW(8);
    SBAR();
    for (int h = 0; h < NH - 3; ++h) G1_PH(h, VMW(8), 1);
    G1_PH(NH - 3, VMW(4), 0);
    G1_PH(NH - 2, VMW(0), 0);
    G1_PH(NH - 1, VMW(0), 0);

#pragma unroll
    for (int mf = 0; mf < 8; ++mf) {
        int row = row0 + wm * 128 + mf * 16 + lg4 * 4;
#pragma unroll
        for (int nf = 0; nf < 2; ++nf) {
            int col = col0 + wn * 32 + nf * 16 + lr;
#pragma unroll
            for (int rr = 0; rr < 4; ++rr) {
                float g = accg[mf][nf][rr], u = accu[mf][nf][rr];
                float val = g / (1.f + __expf(-g)) * u;
                hmid[(size_t)(row + rr) * IDIM + col] = f2bf(val);
            }
        }
    }
#undef G1_STAGE
#undef G1_PH
}

// ================= GEMM2: out = Hm @ Wd^T (+ hs). BM=256, BN=128, 4x24KB ring.
// SHARED=0 (routed, FIRST): out[tok] = acc. SHARED=1 (shared, SECOND): out += hs + acc.
template <int SHARED>
__global__ __launch_bounds__(512, 2) void gemm2_k(
    const ushort_t* __restrict__ Hm, const ushort_t* __restrict__ Wd,
    const int* __restrict__ pad_off, const int* __restrict__ order,
    const float* __restrict__ hs, float* __restrict__ out, int RT) {
    __shared__ __align__(16) ushort_t lds[4 * 12288];  // 96 KiB
    const int CT = HDIM / 128;           // 8
    const int NH = IDIM / 32;            // 64 halves
    int rt, ct;
    sbmap(blockIdx.x, 1, RT / 4, rt, ct);
    int row0 = rt * 256, col0 = ct * 128;
    const ushort_t* wdp;
    if (SHARED) {
        wdp = Wd + (size_t)8 * HDIM * IDIM;
    } else {
        if (row0 >= pad_off[NEXP]) return;
        int e = 0;
        while (e < 7 && row0 >= pad_off[e + 1]) ++e;
        wdp = Wd + (size_t)e * HDIM * IDIM;
    }
    const int tid = threadIdx.x, l = tid & 63, w = tid >> 6;
    const int wm = w >> 1, wn = w & 1;
    const int lr = l & 15, lg4 = l >> 4;

    int rA0, kA0, rA1, kA1, rB, kB;
    gdec(tid, rA0, kA0);
    gdec(512 + tid, rA1, kA1);
    gdec(tid, rB, kB);
    const ushort_t* srcA0 = Hm + (size_t)(row0 + rA0) * IDIM + kA0 * 8;
    const ushort_t* srcA1 = Hm + (size_t)(row0 + rA1) * IDIM + kA1 * 8;
    const ushort_t* srcB = wdp + (size_t)(col0 + rB) * IDIM + kB * 8;
    const int dA0 = tid * 8, dA1 = (512 + tid) * 8, dB = tid * 8;

    const int s_slot = (((l & 1) << 2) | lg4) ^ ((l >> 1) & 7);
    const int aoff = (wm * 32 + (lr >> 1)) * 64 + s_slot * 8;
    const int boff = (wn * 32 + (lr >> 1)) * 64 + s_slot * 8;

    f32x4 acc[4][4] = {};

#define G2_STAGE(h) do { int ko = (h) * 32; int hb_ = ((h) & 3) * 12288;       \
        gload16(srcA0 + ko, &lds[hb_ + dA0]);                                  \
        gload16(srcA1 + ko, &lds[hb_ + dA1]);                                  \
        gload16(srcB + ko, &lds[hb_ + 8192 + dB]); } while (0)

#define G2_PH(h, VMWAIT, DOSTAGE) do {                                         \
        const int hb = ((h) & 3) * 12288;                                      \
        s16x8 av[4], bv[4];                                                    \
        _Pragma("unroll")                                                      \
        for (int i = 0; i < 4; ++i) av[i] = *(const s16x8*)&lds[hb + aoff + i * 512]; \
        _Pragma("unroll")                                                      \
        for (int i = 0; i < 4; ++i) bv[i] = *(const s16x8*)&lds[hb + 8192 + boff + i * 512]; \
        if (DOSTAGE) G2_STAGE((h) + 3);                                        \
        VMWAIT;                                                                \
        SBAR();                                                                \
        LGKM(0);                                                               \
        __builtin_amdgcn_s_setprio(1);                                         \
        _Pragma("unroll")                                                      \
        for (int m = 0; m < 4; ++m)                                            \
            _Pragma("unroll")                                                  \
            for (int n = 0; n < 4; ++n)                                        \
                acc[m][n] = __builtin_amdgcn_mfma_f32_16x16x32_bf16(av[m], bv[n], acc[m][n], 0, 0, 0); \
        __builtin_amdgcn_s_setprio(0);                                         \
        SBAR();                                                                \
    } while (0)

    G2_STAGE(0);
    G2_STAGE(1);
    G2_STAGE(2);
    VMW(6);
    SBAR();
    for (int h = 0; h < NH - 3; ++h) G2_PH(h, VMW(6), 1);
    G2_PH(NH - 3, VMW(3), 0);
    G2_PH(NH - 2, VMW(0), 0);
    G2_PH(NH - 1, VMW(0), 0);

#pragma unroll
    for (int mf = 0; mf < 4; ++mf) {
        int row = row0 + wm * 64 + mf * 16 + lg4 * 4;
#pragma unroll
        for (int nf = 0; nf < 4; ++nf) {
            int col = col0 + wn * 64 + nf * 16 + lr;
#pragma unroll
            for (int rr = 0; rr < 4; ++rr) {
                int rw_ = row + rr;
                if (SHARED) {
                    size_t o = (size_t)rw_ * HDIM + col;
                    out[o] += hs[o] + acc[mf][nf][rr];
                } else {
                    int tok = order[rw_];
                    if (tok >= 0) {
                        size_t o = (size_t)tok * HDIM + col;
                        out[o] = acc[mf][nf][rr];
                    }
                }
            }
        }
    }
#undef G2_STAGE
#undef G2_PH
}

extern "C" void kernel_launch(void* const* d_in, const int* in_sizes, int n_in,
                              void* d_out, int out_size, void* d_ws, size_t ws_size,
                              hipStream_t stream) {
    const float* hs = (const float*)d_in[0];
    const float* lnw = (const float*)d_in[1];
    const float* lnb = (const float*)d_in[2];
    const float* rw = (const float*)d_in[3];
    const float* gw = (const float*)d_in[4];
    const float* uw = (const float*)d_in[5];
    const float* dw = (const float*)d_in[6];
    const float* shg = (const float*)d_in[7];
    const float* shu = (const float*)d_in[8];
    const float* shd = (const float*)d_in[9];
    float* out = (float*)d_out;

    char* p = (char*)d_ws;
    auto alloc = [&](size_t bytes) {
        void* r = (void*)p;
        p += (bytes + 255) & ~(size_t)255;
        return r;
    };
    ushort_t* xsbuf = (ushort_t*)alloc((size_t)TOTROWS * HDIM * 2);   // routed rows + normed rows
    ushort_t* hmid = (ushort_t*)alloc((size_t)TOTROWS * IDIM * 2);
    ushort_t* gwt = (ushort_t*)alloc((size_t)9 * IDIM * HDIM * 2);    // experts 0-7 + shared(8)
    ushort_t* uwt = (ushort_t*)alloc((size_t)9 * IDIM * HDIM * 2);
    ushort_t* dwt = (ushort_t*)alloc((size_t)9 * HDIM * IDIM * 2);
    int* cnt = (int*)alloc(NEXP * 4);
    int* pad_off = (int*)alloc((NEXP + 1) * 4);
    int* fill = (int*)alloc(NEXP * 4);
    int* top_idx = (int*)alloc(T_TOK * 4);
    float* top_sc = (float*)alloc(T_TOK * 4);
    int* order = (int*)alloc(RPAD_MAX * 4);

    ushort_t* normed = xsbuf + (size_t)RPAD_MAX * HDIM;

    hipMemsetAsync(cnt, 0, NEXP * 4, stream);
    hipMemsetAsync(order, 0xFF, RPAD_MAX * 4, stream);
    hipMemsetAsync(xsbuf, 0, (size_t)RPAD_MAX * HDIM * 2, stream);   // zero pad rows

    // weights transpose+convert (27 matrices of 1024x2048 / 2048x1024)
    tcvt64<<<dim3(IDIM / 64, HDIM / 64, 27), dim3(64, 4), 0, stream>>>(
        gw, shg, uw, shu, dw, shd, gwt, uwt, dwt);

    ln_router<<<T_TOK, 256, 0, stream>>>(hs, lnw, lnb, rw, normed, top_idx, top_sc, cnt);
    scan_k<<<1, 64, 0, stream>>>(cnt, pad_off, fill);
    scatter_k<<<T_TOK, 256, 0, stream>>>(normed, top_idx, top_sc, pad_off, fill, order, xsbuf);

    // fused gemm1 over routed (rows [0,RPAD_MAX)) + shared (rows [RPAD_MAX,TOTROWS))
    {
        int RT = TOTROWS / 256, CT = IDIM / 128;
        gemm1_k<<<RT * CT, 512, 0, stream>>>(xsbuf, gwt, uwt, pad_off, hmid);
    }
    // routed down-proj FIRST: out[tok] = acc (plain store — every token exactly once)
    {
        int RT = RPAD_MAX / 256;  // 40
        gemm2_k<0><<<RT * (HDIM / 128), 512, 0, stream>>>(
            hmid, dwt, pad_off, order, hs, out, RT);
    }
    // shared down-proj SECOND: out += hs + acc
    {
        int RT = T_TOK / 256;  // 32
        gemm2_k<1><<<RT * (HDIM / 128), 512, 0, stream>>>(
            hmid + (size_t)RPAD_MAX * IDIM, dwt, pad_off, order, hs, out, RT);
    }
}

// Round 8
// 563.663 us; speedup vs baseline: 1.4930x; 1.0247x over previous
//
#include <hip/hip_runtime.h>

typedef unsigned short ushort_t;
typedef unsigned int uint_t;

#define T_TOK 8192
#define HDIM 1024
#define IDIM 2048
#define NEXP 8
#define RPAD_MAX 10240                 // 8192 + 8*256 worst-case padded routed rows
#define TOTROWS (RPAD_MAX + T_TOK)     // 18432

using f32x4 = __attribute__((ext_vector_type(4))) float;
using s16x8 = __attribute__((ext_vector_type(8))) short;

#define SBAR() do { asm volatile("" ::: "memory"); __builtin_amdgcn_s_barrier(); asm volatile("" ::: "memory"); } while (0)
#define VMW(n) asm volatile("s_waitcnt vmcnt(" #n ")" ::: "memory")
#define LGKM(n) do { asm volatile("s_waitcnt lgkmcnt(" #n ")" ::: "memory"); __builtin_amdgcn_sched_barrier(0); } while (0)
#define SCHB() __builtin_amdgcn_sched_barrier(0)

__device__ __forceinline__ float b2f(ushort_t h) {
    return __uint_as_float(((uint_t)h) << 16);
}
__device__ __forceinline__ ushort_t f2bf(float f) {
    uint_t u = __float_as_uint(f);
    uint_t r = (u + 0x7FFFu + ((u >> 16) & 1u)) >> 16;
    return (ushort_t)r;
}
__device__ __forceinline__ void gload16(const void* g, void* l) {
    __builtin_amdgcn_global_load_lds(
        (const __attribute__((address_space(1))) void*)g,
        (__attribute__((address_space(3))) void*)l, 16, 0, 0);
}
// 2-D super-block scheduler (XCD locality): 4rt x 8ct rectangle per XCD round.
__device__ __forceinline__ void sbmap(int bid, int SBC, int NSB, int& rt, int& ct) {
    int x = bid & 7, j = bid >> 3;
    int r = j >> 5, pos = j & 31;
    int sb = r * 8 + x;
    int rem = NSB - r * 8;
    if (rem < 8) {
        int share = 8 / rem;
        int cap = 32 / share;
        sb = r * 8 + x / share;
        pos = (x % share) * cap + (pos % cap);
    }
    int sbr = sb / SBC, sbc = sb % SBC;
    rt = sbr * 4 + (pos >> 3);
    ct = sbc * 8 + (pos & 7);
}

// ---------------- transpose + fp32->bf16, 64x64 tiles, ushort4 writes
__global__ void tcvt64(const float* __restrict__ gw, const float* __restrict__ shg,
                       const float* __restrict__ uw, const float* __restrict__ shu,
                       const float* __restrict__ dw, const float* __restrict__ shd,
                       ushort_t* __restrict__ gwt, ushort_t* __restrict__ uwt,
                       ushort_t* __restrict__ dwt) {
    __shared__ float tile[64][65];
    int z = blockIdx.z;
    const float* src;
    ushort_t* dst;
    int R, C, bx = blockIdx.x, by = blockIdx.y;
    if (z < 18) {                       // gate/up: src [H][I], dst [I][H]
        int zz = z % 9;
        R = HDIM; C = IDIM;
        if (z < 9) { src = zz < 8 ? gw + (size_t)zz * HDIM * IDIM : shg; dst = gwt + (size_t)zz * IDIM * HDIM; }
        else       { src = zz < 8 ? uw + (size_t)zz * HDIM * IDIM : shu; dst = uwt + (size_t)zz * IDIM * HDIM; }
    } else {                            // down: src [I][H], dst [H][I]
        int zz = z - 18;
        R = IDIM; C = HDIM;
        src = zz < 8 ? dw + (size_t)zz * IDIM * HDIM : shd;
        dst = dwt + (size_t)zz * HDIM * IDIM;
        int t = bx; bx = by; by = t;
    }
    int c0 = bx * 64, r0 = by * 64;
    int tx = threadIdx.x, ty = threadIdx.y;       // (64,4)
#pragma unroll
    for (int i = 0; i < 16; ++i)
        tile[ty + i * 4][tx] = src[(size_t)(r0 + ty + i * 4) * C + c0 + tx];
    __syncthreads();
    int tid = ty * 64 + tx;
    int rr = (tid & 15) * 4, cc0 = tid >> 4;
#pragma unroll
    for (int it = 0; it < 4; ++it) {
        int c = cc0 + it * 16;
        ushort4 v;
        v.x = f2bf(tile[rr + 0][c]);
        v.y = f2bf(tile[rr + 1][c]);
        v.z = f2bf(tile[rr + 2][c]);
        v.w = f2bf(tile[rr + 3][c]);
        *(ushort4*)&dst[(size_t)(c0 + c) * R + r0 + rr] = v;
    }
}

// ---------------- layernorm + router
__global__ void ln_router(const float* __restrict__ x, const float* __restrict__ lnw,
                          const float* __restrict__ lnb, const float* __restrict__ rw,
                          ushort_t* __restrict__ normed, int* __restrict__ top_idx,
                          float* __restrict__ top_score, int* __restrict__ cnt) {
    int t = blockIdx.x, tid = threadIdx.x;
    const float* xr = x + (size_t)t * HDIM;
    float v[4];
    float s = 0.f, ss = 0.f;
#pragma unroll
    for (int i = 0; i < 4; i++) {
        v[i] = xr[tid + i * 256];
        s += v[i];
        ss += v[i] * v[i];
    }
#pragma unroll
    for (int o = 32; o; o >>= 1) {
        s += __shfl_down(s, o);
        ss += __shfl_down(ss, o);
    }
    __shared__ float rs_[4], rss_[4], stats[2];
    int wid = tid >> 6, lane = tid & 63;
    if (!lane) { rs_[wid] = s; rss_[wid] = ss; }
    __syncthreads();
    if (!tid) {
        float S = rs_[0] + rs_[1] + rs_[2] + rs_[3];
        float SS = rss_[0] + rss_[1] + rss_[2] + rss_[3];
        float mu = S * (1.f / HDIM);
        float var = SS * (1.f / HDIM) - mu * mu;
        stats[0] = mu;
        stats[1] = rsqrtf(var + 1e-5f);
    }
    __syncthreads();
    float mu = stats[0], rsg = stats[1];
    float lg[8] = {0, 0, 0, 0, 0, 0, 0, 0};
#pragma unroll
    for (int i = 0; i < 4; i++) {
        int h = tid + i * 256;
        float xn = (v[i] - mu) * rsg * lnw[h] + lnb[h];
        normed[(size_t)t * HDIM + h] = f2bf(xn);
        const float* rwh = rw + (size_t)h * NEXP;
#pragma unroll
        for (int e = 0; e < 8; e++) lg[e] += xn * rwh[e];
    }
#pragma unroll
    for (int o = 32; o; o >>= 1)
#pragma unroll
        for (int e = 0; e < 8; e++) lg[e] += __shfl_down(lg[e], o);
    __shared__ float lred[4][8];
    if (!lane)
#pragma unroll
        for (int e = 0; e < 8; e++) lred[wid][e] = lg[e];
    __syncthreads();
    if (!tid) {
        float best = -1e30f;
        int bi = 0;
#pragma unroll
        for (int e = 0; e < 8; e++) {
            float L = lred[0][e] + lred[1][e] + lred[2][e] + lred[3][e];
            if (L > best) { best = L; bi = e; }
        }
        top_idx[t] = bi;
        top_score[t] = 1.f / (1.f + __expf(-best));
        atomicAdd(&cnt[bi], 1);
    }
}

__global__ void scan_k(const int* __restrict__ cnt, int* __restrict__ pad_off,
                       int* __restrict__ fill) {
    if (threadIdx.x == 0) {
        int o = 0;
        for (int e = 0; e < NEXP; e++) {
            pad_off[e] = o;
            o += (cnt[e] + 255) & ~255;
        }
        pad_off[NEXP] = o;
    }
    if (threadIdx.x < NEXP) fill[threadIdx.x] = 0;
}

__global__ void scatter_k(const ushort_t* __restrict__ normed, const int* __restrict__ top_idx,
                          const float* __restrict__ top_score, const int* __restrict__ pad_off,
                          int* __restrict__ fill, int* __restrict__ order,
                          ushort_t* __restrict__ xs) {
    int t = blockIdx.x, tid = threadIdx.x;
    __shared__ int spos;
    if (!tid) {
        int e = top_idx[t];
        int p = pad_off[e] + atomicAdd(&fill[e], 1);
        order[p] = t;
        spos = p;
    }
    __syncthreads();
    int pos = spos;
    float sc = top_score[t];
    const ushort4* src = (const ushort4*)(normed + (size_t)t * HDIM);
    ushort4* dst = (ushort4*)(xs + (size_t)pos * HDIM);
    ushort4 a = src[tid];
    a.x = f2bf(b2f(a.x) * sc);
    a.y = f2bf(b2f(a.y) * sc);
    a.z = f2bf(b2f(a.z) * sc);
    a.w = f2bf(b2f(a.w) * sc);
    dst[tid] = a;
}

// ================= GEMM1 (fused routed+shared): hmid = silu(X@Wg^T)*(X@Wu^T)
// BM=256, BN=128g+128u, K-step 64, ring-2 (64KB buffers), ONE barrier/phase.
// Per phase: 24 ds_read -> 8 gload_lds -> lgkm(12) 32 MFMA -> lgkm(0) 32 MFMA
// -> vmcnt(0) (hidden: loads had the whole MFMA cluster in flight) -> s_barrier.
__global__ __launch_bounds__(512, 2) void gemm1_k(
    const ushort_t* __restrict__ X, const ushort_t* __restrict__ Wg,
    const ushort_t* __restrict__ Wu, const int* __restrict__ pad_off,
    ushort_t* __restrict__ hmid) {
    __shared__ __align__(16) ushort_t lds[2 * 32768];  // 128 KiB
    const int CT = IDIM / 128;                       // 16
    const int NH = HDIM / 64;                        // 16 phases
    int rt, ct;
    sbmap(blockIdx.x, CT / 8, (TOTROWS / 256 / 4) * (CT / 8), rt, ct);
    int row0 = rt * 256, col0 = ct * 128;
    int e;
    if (row0 >= RPAD_MAX) e = 8;
    else {
        if (row0 >= pad_off[NEXP]) return;
        e = 0;
        while (e < 7 && row0 >= pad_off[e + 1]) ++e;
    }
    const ushort_t* wgp = Wg + (size_t)e * IDIM * HDIM;
    const ushort_t* wup = Wu + (size_t)e * IDIM * HDIM;

    const int tid = threadIdx.x, l = tid & 63, w = tid >> 6;
    const int wm = w >> 2, wn = w & 3;
    const int lr = l & 15, lg4 = l >> 4;

    // ---- staging sources: granule gi -> row=gi>>3, kg=(gi&7)^(row&7) (XOR involution)
    const ushort_t* sA[4];
#pragma unroll
    for (int j = 0; j < 4; ++j) {
        int gi = tid + j * 512, row = gi >> 3, kg = (gi & 7) ^ (row & 7);
        sA[j] = X + (size_t)(row0 + row) * HDIM + kg * 8;
    }
    const ushort_t *sBg[2], *sBu[2];
#pragma unroll
    for (int j = 0; j < 2; ++j) {
        int gi = tid + j * 512, row = gi >> 3, kg = (gi & 7) ^ (row & 7);
        sBg[j] = wgp + (size_t)(col0 + row) * HDIM + kg * 8;
        sBu[j] = wup + (size_t)(col0 + row) * HDIM + kg * 8;
    }
    // ---- ds_read constants: frag(m,s): off = (rowbase+m*16)*64 + ((s*4+lg4)^(lr&7))*8
    const int sl0 = (lg4 ^ (lr & 7)) * 8, sl1 = ((4 + lg4) ^ (lr & 7)) * 8;
    const int aob = (wm * 128 + lr) * 64;
    const int bob = (wn * 32 + lr) * 64;

    f32x4 accg[8][2] = {};
    f32x4 accu[8][2] = {};

#define G1_STAGE(h) do { int ko = (h) * 64; int hb_ = ((h) & 1) * 32768;       \
        gload16(sA[0] + ko, &lds[hb_ + tid * 8]);                              \
        gload16(sA[1] + ko, &lds[hb_ + 4096 + tid * 8]);                       \
        gload16(sA[2] + ko, &lds[hb_ + 8192 + tid * 8]);                       \
        gload16(sA[3] + ko, &lds[hb_ + 12288 + tid * 8]);                      \
        gload16(sBg[0] + ko, &lds[hb_ + 16384 + tid * 8]);                     \
        gload16(sBg[1] + ko, &lds[hb_ + 20480 + tid * 8]);                     \
        gload16(sBu[0] + ko, &lds[hb_ + 24576 + tid * 8]);                     \
        gload16(sBu[1] + ko, &lds[hb_ + 28672 + tid * 8]); } while (0)

#define G1_PH(h, DOSTAGE) do {                                                 \
        const int hb = ((h) & 1) * 32768;                                      \
        s16x8 a0[8], a1[8], b0[4], b1[4];                                      \
        _Pragma("unroll")                                                      \
        for (int m = 0; m < 8; ++m) a0[m] = *(const s16x8*)&lds[hb + aob + m * 1024 + sl0]; \
        _Pragma("unroll")                                                      \
        for (int n = 0; n < 2; ++n) {                                          \
            b0[n] = *(const s16x8*)&lds[hb + 16384 + bob + n * 1024 + sl0];    \
            b0[2 + n] = *(const s16x8*)&lds[hb + 24576 + bob + n * 1024 + sl0]; \
        }                                                                      \
        SCHB();                                                                \
        _Pragma("unroll")                                                      \
        for (int m = 0; m < 8; ++m) a1[m] = *(const s16x8*)&lds[hb + aob + m * 1024 + sl1]; \
        _Pragma("unroll")                                                      \
        for (int n = 0; n < 2; ++n) {                                          \
            b1[n] = *(const s16x8*)&lds[hb + 16384 + bob + n * 1024 + sl1];    \
            b1[2 + n] = *(const s16x8*)&lds[hb + 24576 + bob + n * 1024 + sl1]; \
        }                                                                      \
        SCHB();                                                                \
        if (DOSTAGE) G1_STAGE((h) + 1);                                        \
        LGKM(12);                                                              \
        __builtin_amdgcn_s_setprio(1);                                         \
        _Pragma("unroll")                                                      \
        for (int m = 0; m < 8; ++m) {                                          \
            accg[m][0] = __builtin_amdgcn_mfma_f32_16x16x32_bf16(a0[m], b0[0], accg[m][0], 0, 0, 0); \
            accg[m][1] = __builtin_amdgcn_mfma_f32_16x16x32_bf16(a0[m], b0[1], accg[m][1], 0, 0, 0); \
            accu[m][0] = __builtin_amdgcn_mfma_f32_16x16x32_bf16(a0[m], b0[2], accu[m][0], 0, 0, 0); \
            accu[m][1] = __builtin_amdgcn_mfma_f32_16x16x32_bf16(a0[m], b0[3], accu[m][1], 0, 0, 0); \
        }                                                                      \
        __builtin_amdgcn_s_setprio(0);                                         \
        LGKM(0);                                                               \
        __builtin_amdgcn_s_setprio(1);                                         \
        _Pragma("unroll")                                                      \
        for (int m = 0; m < 8; ++m) {                                          \
            accg[m][0] = __builtin_amdgcn_mfma_f32_16x16x32_bf16(a1[m], b1[0], accg[m][0], 0, 0, 0); \
            accg[m][1] = __builtin_amdgcn_mfma_f32_16x16x32_bf16(a1[m], b1[1], accg[m][1], 0, 0, 0); \
            accu[m][0] = __builtin_amdgcn_mfma_f32_16x16x32_bf16(a1[m], b1[2], accu[m][0], 0, 0, 0); \
            accu[m][1] = __builtin_amdgcn_mfma_f32_16x16x32_bf16(a1[m], b1[3], accu[m][1], 0, 0, 0); \
        }                                                                      \
        __builtin_amdgcn_s_setprio(0);                                         \
        VMW(0);                                                                \
        SBAR();                                                                \
    } while (0)

    G1_STAGE(0);
    VMW(0);
    SBAR();
    for (int h = 0; h < NH - 1; ++h) G1_PH(h, 1);
    G1_PH(NH - 1, 0);

#pragma unroll
    for (int mf = 0; mf < 8; ++mf) {
        int row = row0 + wm * 128 + mf * 16 + lg4 * 4;
#pragma unroll
        for (int nf = 0; nf < 2; ++nf) {
            int col = col0 + wn * 32 + nf * 16 + lr;
#pragma unroll
            for (int rr = 0; rr < 4; ++rr) {
                float g = accg[mf][nf][rr], u = accu[mf][nf][rr];
                float val = g / (1.f + __expf(-g)) * u;
                hmid[(size_t)(row + rr) * IDIM + col] = f2bf(val);
            }
        }
    }
#undef G1_STAGE
#undef G1_PH
}

// ================= GEMM2: out = Hm @ Wd^T (+ hs). BM=256, BN=128, K-step 64, ring-2.
// SHARED=0 (routed, FIRST): out[tok] = acc. SHARED=1 (shared, SECOND): out += hs + acc.
template <int SHARED>
__global__ __launch_bounds__(512, 2) void gemm2_k(
    const ushort_t* __restrict__ Hm, const ushort_t* __restrict__ Wd,
    const int* __restrict__ pad_off, const int* __restrict__ order,
    const float* __restrict__ hs, float* __restrict__ out, int RT) {
    __shared__ __align__(16) ushort_t lds[2 * 24576];  // 96 KiB
    const int NH = IDIM / 64;            // 32 phases
    int rt, ct;
    sbmap(blockIdx.x, 1, RT / 4, rt, ct);
    int row0 = rt * 256, col0 = ct * 128;
    const ushort_t* wdp;
    if (SHARED) {
        wdp = Wd + (size_t)8 * HDIM * IDIM;
    } else {
        if (row0 >= pad_off[NEXP]) return;
        int e = 0;
        while (e < 7 && row0 >= pad_off[e + 1]) ++e;
        wdp = Wd + (size_t)e * HDIM * IDIM;
    }
    const int tid = threadIdx.x, l = tid & 63, w = tid >> 6;
    const int wm = w >> 1, wn = w & 1;
    const int lr = l & 15, lg4 = l >> 4;

    const ushort_t* sA[4];
#pragma unroll
    for (int j = 0; j < 4; ++j) {
        int gi = tid + j * 512, row = gi >> 3, kg = (gi & 7) ^ (row & 7);
        sA[j] = Hm + (size_t)(row0 + row) * IDIM + kg * 8;
    }
    const ushort_t* sB[2];
#pragma unroll
    for (int j = 0; j < 2; ++j) {
        int gi = tid + j * 512, row = gi >> 3, kg = (gi & 7) ^ (row & 7);
        sB[j] = wdp + (size_t)(col0 + row) * IDIM + kg * 8;
    }
    const int sl0 = (lg4 ^ (lr & 7)) * 8, sl1 = ((4 + lg4) ^ (lr & 7)) * 8;
    const int aob = (wm * 64 + lr) * 64;
    const int bob = (wn * 64 + lr) * 64;

    f32x4 acc[4][4] = {};

#define G2_STAGE(h) do { int ko = (h) * 64; int hb_ = ((h) & 1) * 24576;       \
        gload16(sA[0] + ko, &lds[hb_ + tid * 8]);                              \
        gload16(sA[1] + ko, &lds[hb_ + 4096 + tid * 8]);                       \
        gload16(sA[2] + ko, &lds[hb_ + 8192 + tid * 8]);                       \
        gload16(sA[3] + ko, &lds[hb_ + 12288 + tid * 8]);                      \
        gload16(sB[0] + ko, &lds[hb_ + 16384 + tid * 8]);                      \
        gload16(sB[1] + ko, &lds[hb_ + 20480 + tid * 8]); } while (0)

#define G2_PH(h, DOSTAGE) do {                                                 \
        const int hb = ((h) & 1) * 24576;                                      \
        s16x8 a0[4], a1[4], b0[4], b1[4];                                      \
        _Pragma("unroll")                                                      \
        for (int m = 0; m < 4; ++m) a0[m] = *(const s16x8*)&lds[hb + aob + m * 1024 + sl0]; \
        _Pragma("unroll")                                                      \
        for (int n = 0; n < 4; ++n) b0[n] = *(const s16x8*)&lds[hb + 16384 + bob + n * 1024 + sl0]; \
        SCHB();                                                                \
        _Pragma("unroll")                                                      \
        for (int m = 0; m < 4; ++m) a1[m] = *(const s16x8*)&lds[hb + aob + m * 1024 + sl1]; \
        _Pragma("unroll")                                                      \
        for (int n = 0; n < 4; ++n) b1[n] = *(const s16x8*)&lds[hb + 16384 + bob + n * 1024 + sl1]; \
        SCHB();                                                                \
        if (DOSTAGE) G2_STAGE((h) + 1);                                        \
        LGKM(8);                                                               \
        __builtin_amdgcn_s_setprio(1);                                         \
        _Pragma("unroll")                                                      \
        for (int m = 0; m < 4; ++m)                                            \
            _Pragma("unroll")                                                  \
            for (int n = 0; n < 4; ++n)                                        \
                acc[m][n] = __builtin_amdgcn_mfma_f32_16x16x32_bf16(a0[m], b0[n], acc[m][n], 0, 0, 0); \
        __builtin_amdgcn_s_setprio(0);                                         \
        LGKM(0);                                                               \
        __builtin_amdgcn_s_setprio(1);                                         \
        _Pragma("unroll")                                                      \
        for (int m = 0; m < 4; ++m)                                            \
            _Pragma("unroll")                                                  \
            for (int n = 0; n < 4; ++n)                                        \
                acc[m][n] = __builtin_amdgcn_mfma_f32_16x16x32_bf16(a1[m], b1[n], acc[m][n], 0, 0, 0); \
        __builtin_amdgcn_s_setprio(0);                                         \
        VMW(0);                                                                \
        SBAR();                                                                \
    } while (0)

    G2_STAGE(0);
    VMW(0);
    SBAR();
    for (int h = 0; h < NH - 1; ++h) G2_PH(h, 1);
    G2_PH(NH - 1, 0);

#pragma unroll
    for (int mf = 0; mf < 4; ++mf) {
        int row = row0 + wm * 64 + mf * 16 + lg4 * 4;
#pragma unroll
        for (int nf = 0; nf < 4; ++nf) {
            int col = col0 + wn * 64 + nf * 16 + lr;
#pragma unroll
            for (int rr = 0; rr < 4; ++rr) {
                int rw_ = row + rr;
                if (SHARED) {
                    size_t o = (size_t)rw_ * HDIM + col;
                    out[o] += hs[o] + acc[mf][nf][rr];
                } else {
                    int tok = order[rw_];
                    if (tok >= 0) {
                        size_t o = (size_t)tok * HDIM + col;
                        out[o] = acc[mf][nf][rr];
                    }
                }
            }
        }
    }
#undef G2_STAGE
#undef G2_PH
}

extern "C" void kernel_launch(void* const* d_in, const int* in_sizes, int n_in,
                              void* d_out, int out_size, void* d_ws, size_t ws_size,
                              hipStream_t stream) {
    const float* hs = (const float*)d_in[0];
    const float* lnw = (const float*)d_in[1];
    const float* lnb = (const float*)d_in[2];
    const float* rw = (const float*)d_in[3];
    const float* gw = (const float*)d_in[4];
    const float* uw = (const float*)d_in[5];
    const float* dw = (const float*)d_in[6];
    const float* shg = (const float*)d_in[7];
    const float* shu = (const float*)d_in[8];
    const float* shd = (const float*)d_in[9];
    float* out = (float*)d_out;

    char* p = (char*)d_ws;
    auto alloc = [&](size_t bytes) {
        void* r = (void*)p;
        p += (bytes + 255) & ~(size_t)255;
        return r;
    };
    ushort_t* xsbuf = (ushort_t*)alloc((size_t)TOTROWS * HDIM * 2);   // routed rows + normed rows
    ushort_t* hmid = (ushort_t*)alloc((size_t)TOTROWS * IDIM * 2);
    ushort_t* gwt = (ushort_t*)alloc((size_t)9 * IDIM * HDIM * 2);    // experts 0-7 + shared(8)
    ushort_t* uwt = (ushort_t*)alloc((size_t)9 * IDIM * HDIM * 2);
    ushort_t* dwt = (ushort_t*)alloc((size_t)9 * HDIM * IDIM * 2);
    int* cnt = (int*)alloc(NEXP * 4);
    int* pad_off = (int*)alloc((NEXP + 1) * 4);
    int* fill = (int*)alloc(NEXP * 4);
    int* top_idx = (int*)alloc(T_TOK * 4);
    float* top_sc = (float*)alloc(T_TOK * 4);
    int* order = (int*)alloc(RPAD_MAX * 4);

    ushort_t* normed = xsbuf + (size_t)RPAD_MAX * HDIM;

    hipMemsetAsync(cnt, 0, NEXP * 4, stream);
    hipMemsetAsync(order, 0xFF, RPAD_MAX * 4, stream);
    hipMemsetAsync(xsbuf, 0, (size_t)RPAD_MAX * HDIM * 2, stream);   // zero pad rows

    // weights transpose+convert (27 matrices)
    tcvt64<<<dim3(IDIM / 64, HDIM / 64, 27), dim3(64, 4), 0, stream>>>(
        gw, shg, uw, shu, dw, shd, gwt, uwt, dwt);

    ln_router<<<T_TOK, 256, 0, stream>>>(hs, lnw, lnb, rw, normed, top_idx, top_sc, cnt);
    scan_k<<<1, 64, 0, stream>>>(cnt, pad_off, fill);
    scatter_k<<<T_TOK, 256, 0, stream>>>(normed, top_idx, top_sc, pad_off, fill, order, xsbuf);

    // fused gemm1 over routed (rows [0,RPAD_MAX)) + shared (rows [RPAD_MAX,TOTROWS))
    {
        int RT = TOTROWS / 256, CT = IDIM / 128;
        gemm1_k<<<RT * CT, 512, 0, stream>>>(xsbuf, gwt, uwt, pad_off, hmid);
    }
    // routed down-proj FIRST: out[tok] = acc (plain store — every token exactly once)
    {
        int RT = RPAD_MAX / 256;  // 40
        gemm2_k<0><<<RT * (HDIM / 128), 512, 0, stream>>>(
            hmid, dwt, pad_off, order, hs, out, RT);
    }
    // shared down-proj SECOND: out += hs + acc
    {
        int RT = T_TOK / 256;  // 32
        gemm2_k<1><<<RT * (HDIM / 128), 512, 0, stream>>>(
            hmid + (size_t)RPAD_MAX * IDIM, dwt, pad_off, order, hs, out, RT);
    }
}